// Round 11
// baseline (378.720 us; speedup 1.0000x reference)
//
#include <hip/hip_runtime.h>
#include <math.h>

#define C64 64
#define CIN 66
#define NCLS 101
#define LDALL 112          // bf16 row stride for unified cls+reg+obj buffer
#define SEG_BLOCKS 2048    // fixed grid for segmax kernels (deterministic stats slots)
#define NPB 1024           // nodes per bucket (CSR build)
#define KMAX 128           // max buckets
#define BINB 512           // binning blocks

typedef float f4 __attribute__((ext_vector_type(4)));
typedef float f2 __attribute__((ext_vector_type(2)));
typedef short s8 __attribute__((ext_vector_type(8)));   // 8 bf16 = 4 VGPRs (MFMA frag)

// bf16 helpers (RNE pack, shift expand)
__device__ __forceinline__ unsigned short f2bf(float f) {
    unsigned int u = __float_as_uint(f);
    u += 0x7fffu + ((u >> 16) & 1u);
    return (unsigned short)(u >> 16);
}
__device__ __forceinline__ unsigned int packbf(float a, float b) {
    return (unsigned int)f2bf(a) | ((unsigned int)f2bf(b) << 16);
}
__device__ __forceinline__ f2 bf2(unsigned int u) {
    f2 r;
    r.x = __uint_as_float(u << 16);
    r.y = __uint_as_float(u & 0xffff0000u);
    return r;
}

// ---------------- CSR build: two-level bucket sort ----------------

__global__ __launch_bounds__(256)
void hist_kernel(const int* __restrict__ dst, int* __restrict__ ghist, int E, int K) {
    __shared__ int lhist[KMAX];
    int b = blockIdx.x;
    int C = (E + gridDim.x - 1) / gridDim.x;
    int lo = b * C, hi = lo + C; if (hi > E) hi = E;
    for (int k = threadIdx.x; k < K; k += 256) lhist[k] = 0;
    __syncthreads();
    for (int e = lo + threadIdx.x; e < hi; e += 256)
        atomicAdd(&lhist[dst[e] >> 10], 1);
    __syncthreads();
    for (int k = threadIdx.x; k < K; k += 256) ghist[k * BINB + b] = lhist[k];
}

__global__ __launch_bounds__(BINB)
void scan_hist_kernel(int* __restrict__ ghist, int* __restrict__ tot, int K) {
    __shared__ int buf[2][BINB];
    int k = blockIdx.x;
    int t = threadIdx.x;
    int v = ghist[k * BINB + t];
    buf[0][t] = v;
    __syncthreads();
    int cur = 0;
    for (int off = 1; off < BINB; off <<= 1) {
        int nv = buf[cur][t];
        if (t >= off) nv += buf[cur][t - off];
        buf[cur ^ 1][t] = nv;
        cur ^= 1;
        __syncthreads();
    }
    ghist[k * BINB + t] = buf[cur][t] - v;
    if (t == BINB - 1) tot[k] = buf[cur][t];
}

__global__ __launch_bounds__(KMAX)
void scan_tot_kernel(const int* __restrict__ tot, int* __restrict__ bstart,
                     int* __restrict__ offs, int K, int N, int E) {
    __shared__ int buf[2][KMAX];
    int t = threadIdx.x;
    int v = (t < K) ? tot[t] : 0;
    buf[0][t] = v;
    __syncthreads();
    int cur = 0;
    for (int off = 1; off < KMAX; off <<= 1) {
        int nv = buf[cur][t];
        if (t >= off) nv += buf[cur][t - off];
        buf[cur ^ 1][t] = nv;
        cur ^= 1;
        __syncthreads();
    }
    if (t < K) bstart[t] = buf[cur][t] - v;
    if (t == 0) { bstart[K] = E; offs[N] = E; }
}

__global__ __launch_bounds__(256)
void scatter_kernel(const int* __restrict__ src, const int* __restrict__ dst,
                    const int* __restrict__ ghist, const int* __restrict__ bstart,
                    unsigned int* __restrict__ staged, int E, int K) {
    __shared__ int lbase[KMAX];
    int b = blockIdx.x;
    int C = (E + gridDim.x - 1) / gridDim.x;
    int lo = b * C, hi = lo + C; if (hi > E) hi = E;
    for (int k = threadIdx.x; k < K; k += 256)
        lbase[k] = bstart[k] + ghist[k * BINB + b];
    __syncthreads();
    for (int e = lo + threadIdx.x; e < hi; e += 256) {
        int d = dst[e];
        int k = d >> 10;
        int p = atomicAdd(&lbase[k], 1);
        staged[p] = (unsigned int)src[e] | ((unsigned int)(d & (NPB - 1)) << 17);
    }
}

__global__ __launch_bounds__(1024)
void build_kernel(const unsigned int* __restrict__ staged, const int* __restrict__ bstart,
                  int* __restrict__ offs, int* __restrict__ csr, int N) {
    __shared__ int cnt[1024];
    __shared__ int buf[1024];
    int k = blockIdx.x;
    int t = threadIdx.x;
    int e0 = bstart[k], e1 = bstart[k + 1];
    cnt[t] = 0;
    __syncthreads();
    for (int p = e0 + t; p < e1; p += 1024)
        atomicAdd(&cnt[staged[p] >> 17], 1);
    __syncthreads();
    int myc = cnt[t];
    int* a = cnt; int* bb = buf;
    for (int off = 1; off < 1024; off <<= 1) {
        int v = a[t];
        if (t >= off) v += a[t - off];
        bb[t] = v;
        __syncthreads();
        int* tmp = a; a = bb; bb = tmp;
    }
    int excl = a[t] - myc;
    int node = k * NPB + t;
    if (node < N) offs[node] = e0 + excl;
    bb[t] = excl;
    __syncthreads();
    for (int p = e0 + t; p < e1; p += 1024) {
        unsigned int v = staged[p];
        int n = v >> 17;
        int q = atomicAdd(&bb[n], 1);
        csr[e0 + q] = (int)(v & 0x1FFFFu);
    }
}

// ---------------- MFMA GEMM: U = [feat|pos2] @ W^T + b -> bf16 ----------------

template <bool BF16IN, bool SAMEW>
__global__ __launch_bounds__(256)
void gemm_mfma(const void* __restrict__ feat_, const float* __restrict__ pos,
               const float* __restrict__ Wa, const float* __restrict__ ba,
               const float* __restrict__ Wb, const float* __restrict__ bb,
               const float* __restrict__ ab, unsigned short* __restrict__ U,
               int N, int WROWS, int ldU) {
    __shared__ __attribute__((aligned(16))) unsigned short As[64][104];
    __shared__ __attribute__((aligned(16))) unsigned short Bs[64][104];
    int row0    = blockIdx.x * 64;
    int colbase = blockIdx.y * 64;
    const float* W  = blockIdx.y ? Wb : Wa;
    const float* bi = blockIdx.y ? bb : ba;
    int wbase = SAMEW ? colbase : 0;
    int tid  = threadIdx.x;

    for (int idx = tid; idx < 64 * 52; idx += 256) {
        int r = idx / 52, k2 = idx - r * 52;
        int grow = row0 + r;
        unsigned int pack = 0;
        if (grow < N && k2 <= 32) {
            float v0, v1;
            if (k2 < 32) {
                if (BF16IN) {
                    f2 v = bf2(((const unsigned int*)feat_)[(size_t)grow * 32 + k2]);
                    v0 = v.x; v1 = v.y;
                } else {
                    f2 v = *(const f2*)&((const float*)feat_)[(size_t)grow * 64 + k2 * 2];
                    v0 = v.x; v1 = v.y;
                }
                if (ab) {
                    int k = k2 * 2;
                    v0 = fmaxf(0.f, v0 * ab[k] + ab[64 + k]);
                    v1 = fmaxf(0.f, v1 * ab[k + 1] + ab[64 + k + 1]);
                }
            } else {
                v0 = pos[(size_t)grow * 3 + 0];
                v1 = pos[(size_t)grow * 3 + 1];
            }
            pack = packbf(v0, v1);
        }
        *(unsigned int*)&As[r][k2 * 2] = pack;
    }
    for (int idx = tid; idx < 64 * 52; idx += 256) {
        int c = idx / 52, k2 = idx - c * 52;
        unsigned int pack = 0;
        int wrow = wbase + c;
        if (wrow < WROWS && k2 <= 32) {
            f2 v = *(const f2*)&W[(size_t)wrow * 66 + k2 * 2];
            pack = packbf(v.x, v.y);
        }
        *(unsigned int*)&Bs[c][k2 * 2] = pack;
    }
    __syncthreads();

    int lane = tid & 63;
    int wv   = tid >> 6;
    int l16  = lane & 15;
    int kg   = lane >> 4;
    int wr   = wv * 16;

    f4 acc[4];
#pragma unroll
    for (int t = 0; t < 4; ++t) acc[t] = (f4)(0.f);

#pragma unroll
    for (int s = 0; s < 3; ++s) {
        s8 a = *(const s8*)&As[wr + l16][s * 32 + kg * 8];
#pragma unroll
        for (int t = 0; t < 4; ++t) {
            s8 b = *(const s8*)&Bs[t * 16 + l16][s * 32 + kg * 8];
            acc[t] = __builtin_amdgcn_mfma_f32_16x16x32_bf16(a, b, acc[t], 0, 0, 0);
        }
    }

#pragma unroll
    for (int t = 0; t < 4; ++t) {
        int cl   = t * 16 + l16;
        int wrow = wbase + cl;
        if (wrow >= WROWS) continue;
        int gc = colbase + cl;
        float bv = bi[wrow];
#pragma unroll
        for (int r = 0; r < 4; ++r) {
            int grow = row0 + wr + kg * 4 + r;
            if (grow < N)
                U[(size_t)grow * ldU + gc] = f2bf(acc[t][r] + bv);
        }
    }
}

// ---------------- reg(4)+obj(1) heads (bf16 in, bf16 out -> uAll cols 102..106) ----------------

__global__ __launch_bounds__(256)
void gemm_regobj(const unsigned int* __restrict__ sb, const float* __restrict__ pos,
                 const float* __restrict__ Wr, const float* __restrict__ br,
                 const float* __restrict__ Wo, const float* __restrict__ bo,
                 const float* __restrict__ ab, unsigned short* __restrict__ uAll, int N) {
    __shared__ __attribute__((aligned(16))) float As[64][68];
    __shared__ float Wt[66][5];
    int row0 = blockIdx.x * 64;
    int tid  = threadIdx.x;
    for (int idx = tid; idx < 64 * 33; idx += 256) {
        int r = idx / 33, k2 = idx - r * 33;
        int grow = row0 + r;
        float v0 = 0.f, v1 = 0.f;
        if (grow < N) {
            if (k2 < 32) {
                f2 v = bf2(sb[(size_t)grow * 32 + k2]);
                int k = k2 * 2;
                v0 = fmaxf(0.f, v.x * ab[k] + ab[64 + k]);
                v1 = fmaxf(0.f, v.y * ab[k + 1] + ab[64 + k + 1]);
            } else {
                v0 = pos[(size_t)grow * 3 + 0];
                v1 = pos[(size_t)grow * 3 + 1];
            }
        }
        As[r][k2 * 2]     = v0;
        As[r][k2 * 2 + 1] = v1;
    }
    for (int idx = tid; idx < 66 * 5; idx += 256) {
        int c = idx / 66, k = idx - c * 66;
        Wt[k][c] = (c < 4) ? Wr[(size_t)c * 66 + k] : Wo[k];
    }
    __syncthreads();
    int r  = tid & 63;
    int cs = tid >> 6;     // 0..3
    int grow = row0 + r;
    if (grow >= N) return;
    float acc = 0.f, acco = 0.f;
    for (int k = 0; k < 66; ++k) {
        float a = As[r][k];
        acc += a * Wt[k][cs];
        if (cs == 0) acco += a * Wt[k][4];
    }
    uAll[(size_t)grow * LDALL + 102 + cs] = f2bf(acc + br[cs]);
    if (cs == 0) uAll[(size_t)grow * LDALL + 106] = f2bf(acco + bo[0]);
}

// ---------------- segment max, 64ch bf16 (stem): 1 node/wave, 2 edges/instr ----------------
// Half-waves process even/odd edges of the SAME node; merged via shfl_xor(32).

__global__ __launch_bounds__(256)
void segmax64b(const unsigned short* __restrict__ U, const float* __restrict__ pos,
               const float* __restrict__ W, const int* __restrict__ offs,
               const int* __restrict__ csr, unsigned int* __restrict__ outb,
               float* __restrict__ partials, int N) {
    int t    = threadIdx.x;
    int lane = t & 63;
    int h    = lane >> 5;       // edge parity handled by this half-wave
    int cl   = lane & 31;
    int c0   = cl * 2;
    int wv   = t >> 6;
    int gw   = blockIdx.x * 4 + wv;
    int nw   = gridDim.x * 4;
    float wa0 = W[c0 * 66 + 64],       wa1 = W[c0 * 66 + 65];
    float wb0 = W[(c0 + 1) * 66 + 64], wb1 = W[(c0 + 1) * 66 + 65];
    f2 sum = {0.f, 0.f}, sq = {0.f, 0.f};
    for (int i = gw; i < N; i += nw) {
        int s0 = offs[i], s1 = offs[i + 1];
        f2 m = { -INFINITY, -INFINITY };
        int e = s0;
        for (; e + 8 <= s1; e += 8) {       // 4 edge-pairs; this half does edges e+2u+h
            unsigned int v[4];
#pragma unroll
            for (int u = 0; u < 4; ++u)
                v[u] = *(const unsigned int*)&U[(size_t)csr[e + 2 * u + h] * 64 + c0];
#pragma unroll
            for (int u = 0; u < 4; ++u) {
                f2 f = bf2(v[u]);
                m.x = fmaxf(m.x, f.x);
                m.y = fmaxf(m.y, f.y);
            }
        }
        for (; e + 2 <= s1; e += 2) {
            f2 f = bf2(*(const unsigned int*)&U[(size_t)csr[e + h] * 64 + c0]);
            m.x = fmaxf(m.x, f.x);
            m.y = fmaxf(m.y, f.y);
        }
        if (e < s1 && h == 0) {             // odd tail edge
            f2 f = bf2(*(const unsigned int*)&U[(size_t)csr[e] * 64 + c0]);
            m.x = fmaxf(m.x, f.x);
            m.y = fmaxf(m.y, f.y);
        }
        // merge the two half-wave partial maxes (same channels)
        m.x = fmaxf(m.x, __shfl_xor(m.x, 32));
        m.y = fmaxf(m.y, __shfl_xor(m.y, 32));
        if (h == 0) {
            float p0 = pos[i * 3], p1 = pos[i * 3 + 1];
            f2 val = {0.f, 0.f};
            if (s1 > s0) {
                val.x = m.x - (p0 * wa0 + p1 * wa1);
                val.y = m.y - (p0 * wb0 + p1 * wb1);
            }
            outb[(size_t)i * 32 + cl] = packbf(val.x, val.y);
            sum.x += val.x; sum.y += val.y;
            sq.x  += val.x * val.x; sq.y += val.y * val.y;
        }
    }
    __shared__ f2 ls[4][32];
    __shared__ f2 lq[4][32];
    if (h == 0) { ls[wv][cl] = sum; lq[wv][cl] = sq; }
    __syncthreads();
    if (t < 32) {
        f2 S = {0.f, 0.f}, Q = {0.f, 0.f};
#pragma unroll
        for (int w = 0; w < 4; ++w) {
            f2 a = ls[w][t]; S.x += a.x; S.y += a.y;
            f2 c = lq[w][t]; Q.x += c.x; Q.y += c.y;
        }
        partials[blockIdx.x * 128 + 2 * t]       = S.x;
        partials[blockIdx.x * 128 + 2 * t + 1]   = S.y;
        partials[blockIdx.x * 128 + 64 + 2 * t]  = Q.x;
        partials[blockIdx.x * 128 + 65 + 2 * t]  = Q.y;
    }
}

// ---------------- fused dual segment max: 1 node/wave, full 256B-row loads ----------------
// TD row j = [conv1 ch0..63 | conv2 ch0..63] bf16 (256B). Lane l covers bytes l*4:
// lanes 0-31 -> conv1 channels, lanes 32-63 -> conv2 channels. One wave-load per edge.

__global__ __launch_bounds__(256)
void segmax_dual(const unsigned short* __restrict__ TD, const float* __restrict__ pos,
                 const float* __restrict__ W1, const float* __restrict__ W2,
                 const int* __restrict__ offs, const int* __restrict__ csr,
                 unsigned int* __restrict__ S1o, unsigned int* __restrict__ S2o,
                 float* __restrict__ partials, int N) {
    int t    = threadIdx.x;
    int lane = t & 63;
    int cl   = lane & 31;
    int c0   = cl * 2;
    int wv   = t >> 6;
    int gw   = blockIdx.x * 4 + wv;
    int nw   = gridDim.x * 4;
    const float* Ws = (lane >= 32) ? W2 : W1;
    float wa0 = Ws[c0 * 66 + 64],       wa1 = Ws[c0 * 66 + 65];
    float wb0 = Ws[(c0 + 1) * 66 + 64], wb1 = Ws[(c0 + 1) * 66 + 65];
    f2 sum = {0.f, 0.f}, sq = {0.f, 0.f};
    for (int i = gw; i < N; i += nw) {
        int s0 = offs[i], s1 = offs[i + 1];
        f2 m = { -INFINITY, -INFINITY };
        int e = s0;
        for (; e + 8 <= s1; e += 8) {
            unsigned int v[8];
#pragma unroll
            for (int u = 0; u < 8; ++u)
                v[u] = *(const unsigned int*)&TD[(size_t)csr[e + u] * 128 + lane * 2];
#pragma unroll
            for (int u = 0; u < 8; ++u) {
                f2 f = bf2(v[u]);
                m.x = fmaxf(m.x, f.x);
                m.y = fmaxf(m.y, f.y);
            }
        }
        for (; e + 4 <= s1; e += 4) {
            unsigned int v[4];
#pragma unroll
            for (int u = 0; u < 4; ++u)
                v[u] = *(const unsigned int*)&TD[(size_t)csr[e + u] * 128 + lane * 2];
#pragma unroll
            for (int u = 0; u < 4; ++u) {
                f2 f = bf2(v[u]);
                m.x = fmaxf(m.x, f.x);
                m.y = fmaxf(m.y, f.y);
            }
        }
        for (; e < s1; ++e) {
            f2 f = bf2(*(const unsigned int*)&TD[(size_t)csr[e] * 128 + lane * 2]);
            m.x = fmaxf(m.x, f.x);
            m.y = fmaxf(m.y, f.y);
        }
        float p0 = pos[i * 3], p1 = pos[i * 3 + 1];
        f2 val = {0.f, 0.f};
        if (s1 > s0) {
            val.x = m.x - (p0 * wa0 + p1 * wa1);
            val.y = m.y - (p0 * wb0 + p1 * wb1);
        }
        if (lane < 32) S1o[(size_t)i * 32 + cl] = packbf(val.x, val.y);
        else           S2o[(size_t)i * 32 + cl] = packbf(val.x, val.y);
        sum.x += val.x; sum.y += val.y;
        sq.x  += val.x * val.x; sq.y += val.y * val.y;
    }
    __shared__ f2 ls[4][64];
    __shared__ f2 lq[4][64];
    ls[wv][lane] = sum; lq[wv][lane] = sq;
    __syncthreads();
    if (t < 64) {
        f2 S = {0.f, 0.f}, Q = {0.f, 0.f};
#pragma unroll
        for (int w = 0; w < 4; ++w) {
            f2 a = ls[w][t]; S.x += a.x; S.y += a.y;
            f2 c = lq[w][t]; Q.x += c.x; Q.y += c.y;
        }
        float* P = &partials[blockIdx.x * 256];
        if (t < 32) {
            P[2 * t] = S.x;        P[2 * t + 1] = S.y;
            P[64 + 2 * t] = Q.x;   P[65 + 2 * t] = Q.y;
        } else {
            int u = t - 32;
            P[128 + 2 * u] = S.x;  P[129 + 2 * u] = S.y;
            P[192 + 2 * u] = Q.x;  P[193 + 2 * u] = Q.y;
        }
    }
}

// ---------------- unified heads segment max: cls(0..100) + reg(102..105) + obj(106) ----------------

__global__ __launch_bounds__(256)
void segmax_all(const unsigned short* __restrict__ U, const float* __restrict__ pos,
                const float* __restrict__ Wc, const float* __restrict__ Wr,
                const float* __restrict__ Wo, const int* __restrict__ offs,
                const int* __restrict__ csr, float* __restrict__ out_cls,
                float* __restrict__ out_reg, float* __restrict__ out_obj, int N) {
    int lane = threadIdx.x & 63;
    if (lane >= 54) return;               // no barriers below: safe
    int c0 = lane * 2;
    int wv = threadIdx.x >> 6;
    int gg = blockIdx.x * 4 + wv;
    int ng = gridDim.x * 4;
    float w0x, w0y, w1x, w1y;
    if (lane < 51) {
        w0x = Wc[c0 * 66 + 64]; w0y = Wc[c0 * 66 + 65];
        int c1 = c0 + 1;
        w1x = (c1 < NCLS) ? Wc[c1 * 66 + 64] : 0.f;
        w1y = (c1 < NCLS) ? Wc[c1 * 66 + 65] : 0.f;
    } else if (lane < 53) {
        int rc = (lane - 51) * 2;
        w0x = Wr[rc * 66 + 64];       w0y = Wr[rc * 66 + 65];
        w1x = Wr[(rc + 1) * 66 + 64]; w1y = Wr[(rc + 1) * 66 + 65];
    } else {
        w0x = Wo[64]; w0y = Wo[65]; w1x = 0.f; w1y = 0.f;
    }
    for (int i = gg; i < N; i += ng) {
        int s0 = offs[i], s1 = offs[i + 1];
        f2 m = { -INFINITY, -INFINITY };
        int e = s0;
        for (; e + 8 <= s1; e += 8) {
            unsigned int v[8];
#pragma unroll
            for (int u = 0; u < 8; ++u)
                v[u] = *(const unsigned int*)&U[(size_t)csr[e + u] * LDALL + c0];
#pragma unroll
            for (int u = 0; u < 8; ++u) {
                f2 f = bf2(v[u]);
                m.x = fmaxf(m.x, f.x);
                m.y = fmaxf(m.y, f.y);
            }
        }
        for (; e + 4 <= s1; e += 4) {
            unsigned int v[4];
#pragma unroll
            for (int u = 0; u < 4; ++u)
                v[u] = *(const unsigned int*)&U[(size_t)csr[e + u] * LDALL + c0];
#pragma unroll
            for (int u = 0; u < 4; ++u) {
                f2 f = bf2(v[u]);
                m.x = fmaxf(m.x, f.x);
                m.y = fmaxf(m.y, f.y);
            }
        }
        for (; e < s1; ++e) {
            f2 f0 = bf2(*(const unsigned int*)&U[(size_t)csr[e] * LDALL + c0]);
            m.x = fmaxf(m.x, f0.x);
            m.y = fmaxf(m.y, f0.y);
        }
        float p0 = pos[i * 3], p1 = pos[i * 3 + 1];
        float va = 0.f, vb = 0.f;
        if (s1 > s0) {
            va = m.x - (p0 * w0x + p1 * w0y);
            vb = m.y - (p0 * w1x + p1 * w1y);
        }
        if (lane < 50) {
            out_cls[(size_t)i * NCLS + c0]     = va;
            out_cls[(size_t)i * NCLS + c0 + 1] = vb;
        } else if (lane == 50) {
            out_cls[(size_t)i * NCLS + 100] = va;
        } else if (lane == 51) {
            out_reg[(size_t)i * 4 + 0] = va;
            out_reg[(size_t)i * 4 + 1] = vb;
        } else if (lane == 52) {
            out_reg[(size_t)i * 4 + 2] = va;
            out_reg[(size_t)i * 4 + 3] = vb;
        } else {
            out_obj[i] = va;
        }
    }
}

// ---------------- BN finalize: single (stem) and dual (conv1+conv2) ----------------

__global__ __launch_bounds__(1024)
void bn_finalize(const float* __restrict__ partials, int N,
                 const float* __restrict__ g, const float* __restrict__ be,
                 float* __restrict__ ab) {
    __shared__ double ls[16][64];
    __shared__ double lq[16][64];
    int t = threadIdx.x;
    int c  = t & 63;
    int gr = t >> 6;
    double s = 0.0, q = 0.0;
#pragma unroll 8
    for (int b = 0; b < SEG_BLOCKS / 16; ++b) {
        int blk = gr * (SEG_BLOCKS / 16) + b;
        s += (double)partials[blk * 128 + c];
        q += (double)partials[blk * 128 + 64 + c];
    }
    ls[gr][c] = s; lq[gr][c] = q;
    __syncthreads();
    if (gr == 0) {
        double ss = 0.0, qq = 0.0;
#pragma unroll
        for (int i = 0; i < 16; ++i) { ss += ls[i][c]; qq += lq[i][c]; }
        double invN = 1.0 / (double)N;
        float m = (float)(ss * invN);
        float v = (float)(qq * invN) - m * m;
        float a = g[c] * rsqrtf(v + 1e-5f);
        ab[c]      = a;
        ab[64 + c] = be[c] - m * a;
    }
}

__global__ __launch_bounds__(1024)
void bn_finalize2(const float* __restrict__ partials, int N,
                  const float* __restrict__ g1, const float* __restrict__ be1,
                  const float* __restrict__ g2, const float* __restrict__ be2,
                  float* __restrict__ ab1, float* __restrict__ ab2) {
    __shared__ double L[4][16][64];
    int t = threadIdx.x;
    int c  = t & 63;
    int gr = t >> 6;
    double s1 = 0.0, q1 = 0.0, s2 = 0.0, q2 = 0.0;
#pragma unroll 8
    for (int b = 0; b < SEG_BLOCKS / 16; ++b) {
        const float* P = &partials[(size_t)(gr * (SEG_BLOCKS / 16) + b) * 256];
        s1 += (double)P[c];        q1 += (double)P[64 + c];
        s2 += (double)P[128 + c];  q2 += (double)P[192 + c];
    }
    L[0][gr][c] = s1; L[1][gr][c] = q1; L[2][gr][c] = s2; L[3][gr][c] = q2;
    __syncthreads();
    if (gr == 0) {
        double S1 = 0, Q1 = 0, S2 = 0, Q2 = 0;
#pragma unroll
        for (int i = 0; i < 16; ++i) {
            S1 += L[0][i][c]; Q1 += L[1][i][c];
            S2 += L[2][i][c]; Q2 += L[3][i][c];
        }
        double invN = 1.0 / (double)N;
        float m1 = (float)(S1 * invN);
        float v1 = (float)(Q1 * invN) - m1 * m1;
        float a1 = g1[c] * rsqrtf(v1 + 1e-5f);
        ab1[c]      = a1;
        ab1[64 + c] = be1[c] - m1 * a1;
        float m2 = (float)(S2 * invN);
        float v2 = (float)(Q2 * invN) - m2 * m2;
        float a2 = g2[c] * rsqrtf(v2 + 1e-5f);
        ab2[c]      = a2;
        ab2[64 + c] = be2[c] - m2 * a2;
    }
}

// ---------------- launch ----------------

extern "C" void kernel_launch(void* const* d_in, const int* in_sizes, int n_in,
                              void* d_out, int out_size, void* d_ws, size_t ws_size,
                              hipStream_t stream) {
    const float* x       = (const float*)d_in[0];
    const float* pos     = (const float*)d_in[1];
    const int*   ei      = (const int*)d_in[2];
    const float* W_stem  = (const float*)d_in[3];
    const float* b_stem  = (const float*)d_in[4];
    const float* W_conv1 = (const float*)d_in[5];
    const float* b_conv1 = (const float*)d_in[6];
    const float* W_conv2 = (const float*)d_in[7];
    const float* b_conv2 = (const float*)d_in[8];
    const float* W_regr  = (const float*)d_in[9];
    const float* b_regr  = (const float*)d_in[10];
    const float* W_cls   = (const float*)d_in[11];
    const float* b_cls   = (const float*)d_in[12];
    const float* W_obj   = (const float*)d_in[13];
    const float* b_obj   = (const float*)d_in[14];
    const float* g_stem  = (const float*)d_in[15];
    const float* be_stem = (const float*)d_in[16];
    const float* g_conv1 = (const float*)d_in[17];
    const float* be_conv1= (const float*)d_in[18];
    const float* g_conv2 = (const float*)d_in[19];
    const float* be_conv2= (const float*)d_in[20];

    const int N = in_sizes[0] / 64;
    const int E = in_sizes[2] / 2;
    const int* src = ei;
    const int* dst = ei + E;
    const int K = (N + NPB - 1) / NPB;

    // ---- workspace layout (256B-aligned regions) ----
    char* ws = (char*)d_ws;
    size_t off = 0;
    auto carve = [&](size_t bytes) -> char* {
        char* p = ws + off;
        off += (bytes + 255) & ~(size_t)255;
        return p;
    };
    int*   offs     = (int*)carve((size_t)(N + 1) * 4);
    int*   csr      = (int*)carve((size_t)E * 4);
    unsigned int* staged = (unsigned int*)carve((size_t)E * 4);
    int*   ghist    = (int*)carve((size_t)KMAX * BINB * 4);
    int*   tot      = (int*)carve((size_t)KMAX * 4);
    int*   bstart   = (int*)carve((size_t)(KMAX + 1) * 4);
    unsigned int* S1b = (unsigned int*)carve((size_t)N * 32 * 4);   // bf16 [N][64] as u32[N][32]
    unsigned int* S2b = (unsigned int*)carve((size_t)N * 32 * 4);
    unsigned short* T1 = (unsigned short*)carve((size_t)N * 64 * 2);   // U_stem ; (T1+TD) reused as uAll
    unsigned short* TD = (unsigned short*)carve((size_t)N * 128 * 2);  // U1|U2 interleaved
    float* partials = (float*)carve((size_t)SEG_BLOCKS * 256 * 4);
    float* abS      = (float*)carve(128 * 4);
    float* ab1      = (float*)carve(128 * 4);
    float* ab2      = (float*)carve(128 * 4);
    unsigned short* uAll = T1;   // N*112 bf16 = 22.4MB <= T1+TD (38.4MB, contiguous)

    float* out_cls = (float*)d_out;                       // N x 101
    float* out_reg = out_cls + (size_t)N * NCLS;          // N x 4
    float* out_obj = out_reg + (size_t)N * 4;             // N x 1

    const dim3 blk(256);

    // ---- CSR build ----
    hist_kernel<<<BINB, blk, 0, stream>>>(dst, ghist, E, K);
    scan_hist_kernel<<<K, BINB, 0, stream>>>(ghist, tot, K);
    scan_tot_kernel<<<1, KMAX, 0, stream>>>(tot, bstart, offs, K, N, E);
    scatter_kernel<<<BINB, blk, 0, stream>>>(src, dst, ghist, bstart, staged, E, K);
    build_kernel<<<K, 1024, 0, stream>>>(staged, bstart, offs, csr, N);

    const int ng64 = (N + 63) / 64;

    // ---- stem: f32 x -> T1 (bf16) ----
    gemm_mfma<false, true><<<dim3(ng64, 1), blk, 0, stream>>>(
        x, pos, W_stem, b_stem, W_stem, b_stem, nullptr, T1, N, 64, 64);
    segmax64b<<<SEG_BLOCKS, blk, 0, stream>>>(T1, pos, W_stem, offs, csr, S1b, partials, N);
    bn_finalize<<<1, 1024, 0, stream>>>(partials, N, g_stem, be_stem, abS);

    // ---- conv1 + conv2 (one launch, grid.y selects W) -> interleaved TD ----
    gemm_mfma<true, false><<<dim3(ng64, 2), blk, 0, stream>>>(
        S1b, pos, W_conv1, b_conv1, W_conv2, b_conv2, abS, TD, N, 64, 128);
    segmax_dual<<<SEG_BLOCKS, blk, 0, stream>>>(TD, pos, W_conv1, W_conv2, offs, csr,
                                                S1b, S2b, partials, N);
    bn_finalize2<<<1, 1024, 0, stream>>>(partials, N, g_conv1, be_conv1,
                                         g_conv2, be_conv2, ab1, ab2);

    // ---- heads: reg/obj -> uAll cols 102.. ; cls -> uAll cols 0..100 ----
    gemm_regobj<<<dim3(ng64, 1), blk, 0, stream>>>(S1b, pos, W_regr, b_regr,
                                                   W_obj, b_obj, ab1, uAll, N);
    gemm_mfma<true, true><<<dim3(ng64, 2), blk, 0, stream>>>(
        S2b, pos, W_cls, b_cls, W_cls, b_cls, ab2, uAll, N, NCLS, LDALL);

    // ---- unified gather for all three outputs ----
    segmax_all<<<SEG_BLOCKS, blk, 0, stream>>>(uAll, pos, W_cls, W_regr, W_obj,
                                               offs, csr, out_cls, out_reg, out_obj, N);
}

// Round 12
// 347.910 us; speedup vs baseline: 1.0886x; 1.0886x over previous
//
#include <hip/hip_runtime.h>
#include <math.h>

#define C64 64
#define CIN 66
#define NCLS 101
#define LDALL 112          // bf16 row stride for unified cls+reg+obj buffer
#define SEG_BLOCKS 2048    // fixed grid for segmax kernels (deterministic stats slots)
#define NPB 1024           // nodes per bucket (CSR build)
#define KMAX 128           // max buckets
#define BINB 512           // binning blocks

typedef float f4 __attribute__((ext_vector_type(4)));
typedef float f2 __attribute__((ext_vector_type(2)));
typedef short s8 __attribute__((ext_vector_type(8)));   // 8 bf16 = 4 VGPRs (MFMA frag)

// bf16 helpers (RNE pack, shift expand)
__device__ __forceinline__ unsigned short f2bf(float f) {
    unsigned int u = __float_as_uint(f);
    u += 0x7fffu + ((u >> 16) & 1u);
    return (unsigned short)(u >> 16);
}
__device__ __forceinline__ unsigned int packbf(float a, float b) {
    return (unsigned int)f2bf(a) | ((unsigned int)f2bf(b) << 16);
}
__device__ __forceinline__ f2 bf2(unsigned int u) {
    f2 r;
    r.x = __uint_as_float(u << 16);
    r.y = __uint_as_float(u & 0xffff0000u);
    return r;
}

// ---------------- CSR build: two-level bucket sort ----------------

__global__ __launch_bounds__(256)
void hist_kernel(const int* __restrict__ dst, int* __restrict__ ghist, int E, int K) {
    __shared__ int lhist[KMAX];
    int b = blockIdx.x;
    int C = (E + gridDim.x - 1) / gridDim.x;
    int lo = b * C, hi = lo + C; if (hi > E) hi = E;
    for (int k = threadIdx.x; k < K; k += 256) lhist[k] = 0;
    __syncthreads();
    for (int e = lo + threadIdx.x; e < hi; e += 256)
        atomicAdd(&lhist[dst[e] >> 10], 1);
    __syncthreads();
    for (int k = threadIdx.x; k < K; k += 256) ghist[k * BINB + b] = lhist[k];
}

__global__ __launch_bounds__(BINB)
void scan_hist_kernel(int* __restrict__ ghist, int* __restrict__ tot, int K) {
    __shared__ int buf[2][BINB];
    int k = blockIdx.x;
    int t = threadIdx.x;
    int v = ghist[k * BINB + t];
    buf[0][t] = v;
    __syncthreads();
    int cur = 0;
    for (int off = 1; off < BINB; off <<= 1) {
        int nv = buf[cur][t];
        if (t >= off) nv += buf[cur][t - off];
        buf[cur ^ 1][t] = nv;
        cur ^= 1;
        __syncthreads();
    }
    ghist[k * BINB + t] = buf[cur][t] - v;
    if (t == BINB - 1) tot[k] = buf[cur][t];
}

__global__ __launch_bounds__(KMAX)
void scan_tot_kernel(const int* __restrict__ tot, int* __restrict__ bstart,
                     int* __restrict__ offs, int K, int N, int E) {
    __shared__ int buf[2][KMAX];
    int t = threadIdx.x;
    int v = (t < K) ? tot[t] : 0;
    buf[0][t] = v;
    __syncthreads();
    int cur = 0;
    for (int off = 1; off < KMAX; off <<= 1) {
        int nv = buf[cur][t];
        if (t >= off) nv += buf[cur][t - off];
        buf[cur ^ 1][t] = nv;
        cur ^= 1;
        __syncthreads();
    }
    if (t < K) bstart[t] = buf[cur][t] - v;
    if (t == 0) { bstart[K] = E; offs[N] = E; }
}

__global__ __launch_bounds__(256)
void scatter_kernel(const int* __restrict__ src, const int* __restrict__ dst,
                    const int* __restrict__ ghist, const int* __restrict__ bstart,
                    unsigned int* __restrict__ staged, int E, int K) {
    __shared__ int lbase[KMAX];
    int b = blockIdx.x;
    int C = (E + gridDim.x - 1) / gridDim.x;
    int lo = b * C, hi = lo + C; if (hi > E) hi = E;
    for (int k = threadIdx.x; k < K; k += 256)
        lbase[k] = bstart[k] + ghist[k * BINB + b];
    __syncthreads();
    for (int e = lo + threadIdx.x; e < hi; e += 256) {
        int d = dst[e];
        int k = d >> 10;
        int p = atomicAdd(&lbase[k], 1);
        staged[p] = (unsigned int)src[e] | ((unsigned int)(d & (NPB - 1)) << 17);
    }
}

__global__ __launch_bounds__(1024)
void build_kernel(const unsigned int* __restrict__ staged, const int* __restrict__ bstart,
                  int* __restrict__ offs, int* __restrict__ csr, int N) {
    __shared__ int cnt[1024];
    __shared__ int buf[1024];
    int k = blockIdx.x;
    int t = threadIdx.x;
    int e0 = bstart[k], e1 = bstart[k + 1];
    cnt[t] = 0;
    __syncthreads();
    for (int p = e0 + t; p < e1; p += 1024)
        atomicAdd(&cnt[staged[p] >> 17], 1);
    __syncthreads();
    int myc = cnt[t];
    int* a = cnt; int* bb = buf;
    for (int off = 1; off < 1024; off <<= 1) {
        int v = a[t];
        if (t >= off) v += a[t - off];
        bb[t] = v;
        __syncthreads();
        int* tmp = a; a = bb; bb = tmp;
    }
    int excl = a[t] - myc;
    int node = k * NPB + t;
    if (node < N) offs[node] = e0 + excl;
    bb[t] = excl;
    __syncthreads();
    for (int p = e0 + t; p < e1; p += 1024) {
        unsigned int v = staged[p];
        int n = v >> 17;
        int q = atomicAdd(&bb[n], 1);
        csr[e0 + q] = (int)(v & 0x1FFFFu);
    }
}

// ---------------- stem MFMA GEMM (f32 input, single W, 64 cols) ----------------

__global__ __launch_bounds__(256)
void gemm_mfma_stem(const float* __restrict__ feat, const float* __restrict__ pos,
                    const float* __restrict__ W, const float* __restrict__ bi,
                    unsigned short* __restrict__ U, int N) {
    __shared__ __attribute__((aligned(16))) unsigned short As[64][104];
    __shared__ __attribute__((aligned(16))) unsigned short Bs[64][104];
    int row0 = blockIdx.x * 64;
    int tid  = threadIdx.x;

    for (int idx = tid; idx < 64 * 52; idx += 256) {
        int r = idx / 52, k2 = idx - r * 52;
        int grow = row0 + r;
        unsigned int pack = 0;
        if (grow < N && k2 <= 32) {
            float v0, v1;
            if (k2 < 32) {
                f2 v = *(const f2*)&feat[(size_t)grow * 64 + k2 * 2];
                v0 = v.x; v1 = v.y;
            } else {
                v0 = pos[(size_t)grow * 3 + 0];
                v1 = pos[(size_t)grow * 3 + 1];
            }
            pack = packbf(v0, v1);
        }
        *(unsigned int*)&As[r][k2 * 2] = pack;
    }
    for (int idx = tid; idx < 64 * 52; idx += 256) {
        int c = idx / 52, k2 = idx - c * 52;
        unsigned int pack = 0;
        if (k2 <= 32) {
            f2 v = *(const f2*)&W[(size_t)c * 66 + k2 * 2];
            pack = packbf(v.x, v.y);
        }
        *(unsigned int*)&Bs[c][k2 * 2] = pack;
    }
    __syncthreads();

    int lane = tid & 63;
    int wv   = tid >> 6;
    int l16  = lane & 15;
    int kg   = lane >> 4;
    int wr   = wv * 16;

    f4 acc[4];
#pragma unroll
    for (int t = 0; t < 4; ++t) acc[t] = (f4)(0.f);

#pragma unroll
    for (int s = 0; s < 3; ++s) {
        s8 a = *(const s8*)&As[wr + l16][s * 32 + kg * 8];
#pragma unroll
        for (int t = 0; t < 4; ++t) {
            s8 b = *(const s8*)&Bs[t * 16 + l16][s * 32 + kg * 8];
            acc[t] = __builtin_amdgcn_mfma_f32_16x16x32_bf16(a, b, acc[t], 0, 0, 0);
        }
    }

#pragma unroll
    for (int t = 0; t < 4; ++t) {
        int gc = t * 16 + l16;
        float bv = bi[gc];
#pragma unroll
        for (int r = 0; r < 4; ++r) {
            int grow = row0 + wr + kg * 4 + r;
            if (grow < N)
                U[(size_t)grow * 64 + gc] = f2bf(acc[t][r] + bv);
        }
    }
}

// ---------------- dual MFMA GEMM: one A-stage, 128 output cols ----------------
// cols 0..63 <- Wa rows 0..63; cols 64..127 <- Wb rows wbaseB..  (valid < WROWSB).
// bf16 input + fused BN+ReLU. Used for conv1+conv2 (Wb=W2, wbaseB=0) and
// cls (Wb=Wa=Wc, wbaseB=64, WROWSB=101). LDS 40KB -> 4 blocks/CU.

__global__ __launch_bounds__(256)
void gemm_mfma_dual(const unsigned int* __restrict__ sb, const float* __restrict__ pos,
                    const float* __restrict__ Wa, const float* __restrict__ ba,
                    const float* __restrict__ Wb, const float* __restrict__ bb,
                    int wbaseB, int WROWSB, const float* __restrict__ ab,
                    unsigned short* __restrict__ U, int N, int ldU) {
    __shared__ __attribute__((aligned(16))) unsigned short As[64][104];
    __shared__ __attribute__((aligned(16))) unsigned short Bs[128][104];
    int row0 = blockIdx.x * 64;
    int tid  = threadIdx.x;

    for (int idx = tid; idx < 64 * 52; idx += 256) {
        int r = idx / 52, k2 = idx - r * 52;
        int grow = row0 + r;
        unsigned int pack = 0;
        if (grow < N && k2 <= 32) {
            float v0, v1;
            if (k2 < 32) {
                f2 v = bf2(sb[(size_t)grow * 32 + k2]);
                int k = k2 * 2;
                v0 = fmaxf(0.f, v.x * ab[k] + ab[64 + k]);
                v1 = fmaxf(0.f, v.y * ab[k + 1] + ab[64 + k + 1]);
            } else {
                v0 = pos[(size_t)grow * 3 + 0];
                v1 = pos[(size_t)grow * 3 + 1];
            }
            pack = packbf(v0, v1);
        }
        *(unsigned int*)&As[r][k2 * 2] = pack;
    }
    for (int idx = tid; idx < 128 * 52; idx += 256) {
        int c = idx / 52, k2 = idx - c * 52;
        unsigned int pack = 0;
        const float* W = (c < 64) ? Wa : Wb;
        int wrow = (c < 64) ? c : (wbaseB + (c - 64));
        bool valid = (c < 64) ? true : (wrow < WROWSB);
        if (valid && k2 <= 32) {
            f2 v = *(const f2*)&W[(size_t)wrow * 66 + k2 * 2];
            pack = packbf(v.x, v.y);
        }
        *(unsigned int*)&Bs[c][k2 * 2] = pack;
    }
    __syncthreads();

    int lane = tid & 63;
    int wv   = tid >> 6;
    int l16  = lane & 15;
    int kg   = lane >> 4;
    int wr   = wv * 16;

    f4 acc[8];
#pragma unroll
    for (int t = 0; t < 8; ++t) acc[t] = (f4)(0.f);

#pragma unroll
    for (int s = 0; s < 3; ++s) {
        s8 a = *(const s8*)&As[wr + l16][s * 32 + kg * 8];
#pragma unroll
        for (int t = 0; t < 8; ++t) {
            s8 b = *(const s8*)&Bs[t * 16 + l16][s * 32 + kg * 8];
            acc[t] = __builtin_amdgcn_mfma_f32_16x16x32_bf16(a, b, acc[t], 0, 0, 0);
        }
    }

#pragma unroll
    for (int t = 0; t < 8; ++t) {
        int cl = t * 16 + l16;
        float bv;
        bool valid;
        if (cl < 64) { bv = ba[cl]; valid = true; }
        else {
            int wrow = wbaseB + (cl - 64);
            valid = wrow < WROWSB;
            bv = valid ? bb[wrow] : 0.f;
        }
        if (!valid) continue;
#pragma unroll
        for (int r = 0; r < 4; ++r) {
            int grow = row0 + wr + kg * 4 + r;
            if (grow < N)
                U[(size_t)grow * ldU + cl] = f2bf(acc[t][r] + bv);
        }
    }
}

// ---------------- reg(4)+obj(1) heads (bf16 in, bf16 out -> uAll cols 102..106) ----------------

__global__ __launch_bounds__(256)
void gemm_regobj(const unsigned int* __restrict__ sb, const float* __restrict__ pos,
                 const float* __restrict__ Wr, const float* __restrict__ br,
                 const float* __restrict__ Wo, const float* __restrict__ bo,
                 const float* __restrict__ ab, unsigned short* __restrict__ uAll, int N) {
    __shared__ __attribute__((aligned(16))) float As[64][68];
    __shared__ float Wt[66][5];
    int row0 = blockIdx.x * 64;
    int tid  = threadIdx.x;
    for (int idx = tid; idx < 64 * 33; idx += 256) {
        int r = idx / 33, k2 = idx - r * 33;
        int grow = row0 + r;
        float v0 = 0.f, v1 = 0.f;
        if (grow < N) {
            if (k2 < 32) {
                f2 v = bf2(sb[(size_t)grow * 32 + k2]);
                int k = k2 * 2;
                v0 = fmaxf(0.f, v.x * ab[k] + ab[64 + k]);
                v1 = fmaxf(0.f, v.y * ab[k + 1] + ab[64 + k + 1]);
            } else {
                v0 = pos[(size_t)grow * 3 + 0];
                v1 = pos[(size_t)grow * 3 + 1];
            }
        }
        As[r][k2 * 2]     = v0;
        As[r][k2 * 2 + 1] = v1;
    }
    for (int idx = tid; idx < 66 * 5; idx += 256) {
        int c = idx / 66, k = idx - c * 66;
        Wt[k][c] = (c < 4) ? Wr[(size_t)c * 66 + k] : Wo[k];
    }
    __syncthreads();
    int r  = tid & 63;
    int cs = tid >> 6;     // 0..3
    int grow = row0 + r;
    if (grow >= N) return;
    float acc = 0.f, acco = 0.f;
    for (int k = 0; k < 66; ++k) {
        float a = As[r][k];
        acc += a * Wt[k][cs];
        if (cs == 0) acco += a * Wt[k][4];
    }
    uAll[(size_t)grow * LDALL + 102 + cs] = f2bf(acc + br[cs]);
    if (cs == 0) uAll[(size_t)grow * LDALL + 106] = f2bf(acco + bo[0]);
}

// ---------------- segment max, 64ch bf16 (stem): 1 node/wave, 2 edges/instr ----------------

__global__ __launch_bounds__(256)
void segmax64b(const unsigned short* __restrict__ U, const float* __restrict__ pos,
               const float* __restrict__ W, const int* __restrict__ offs,
               const int* __restrict__ csr, unsigned int* __restrict__ outb,
               float* __restrict__ partials, int N) {
    int t    = threadIdx.x;
    int lane = t & 63;
    int h    = lane >> 5;       // edge parity handled by this half-wave
    int cl   = lane & 31;
    int c0   = cl * 2;
    int wv   = t >> 6;
    int gw   = blockIdx.x * 4 + wv;
    int nw   = gridDim.x * 4;
    float wa0 = W[c0 * 66 + 64],       wa1 = W[c0 * 66 + 65];
    float wb0 = W[(c0 + 1) * 66 + 64], wb1 = W[(c0 + 1) * 66 + 65];
    f2 sum = {0.f, 0.f}, sq = {0.f, 0.f};
    for (int i = gw; i < N; i += nw) {
        int s0 = offs[i], s1 = offs[i + 1];
        f2 m = { -INFINITY, -INFINITY };
        int e = s0;
        for (; e + 8 <= s1; e += 8) {
            unsigned int v[4];
#pragma unroll
            for (int u = 0; u < 4; ++u)
                v[u] = *(const unsigned int*)&U[(size_t)csr[e + 2 * u + h] * 64 + c0];
#pragma unroll
            for (int u = 0; u < 4; ++u) {
                f2 f = bf2(v[u]);
                m.x = fmaxf(m.x, f.x);
                m.y = fmaxf(m.y, f.y);
            }
        }
        for (; e + 2 <= s1; e += 2) {
            f2 f = bf2(*(const unsigned int*)&U[(size_t)csr[e + h] * 64 + c0]);
            m.x = fmaxf(m.x, f.x);
            m.y = fmaxf(m.y, f.y);
        }
        if (e < s1 && h == 0) {
            f2 f = bf2(*(const unsigned int*)&U[(size_t)csr[e] * 64 + c0]);
            m.x = fmaxf(m.x, f.x);
            m.y = fmaxf(m.y, f.y);
        }
        m.x = fmaxf(m.x, __shfl_xor(m.x, 32));
        m.y = fmaxf(m.y, __shfl_xor(m.y, 32));
        if (h == 0) {
            float p0 = pos[i * 3], p1 = pos[i * 3 + 1];
            f2 val = {0.f, 0.f};
            if (s1 > s0) {
                val.x = m.x - (p0 * wa0 + p1 * wa1);
                val.y = m.y - (p0 * wb0 + p1 * wb1);
            }
            outb[(size_t)i * 32 + cl] = packbf(val.x, val.y);
            sum.x += val.x; sum.y += val.y;
            sq.x  += val.x * val.x; sq.y += val.y * val.y;
        }
    }
    __shared__ f2 ls[4][32];
    __shared__ f2 lq[4][32];
    if (h == 0) { ls[wv][cl] = sum; lq[wv][cl] = sq; }
    __syncthreads();
    if (t < 32) {
        f2 S = {0.f, 0.f}, Q = {0.f, 0.f};
#pragma unroll
        for (int w = 0; w < 4; ++w) {
            f2 a = ls[w][t]; S.x += a.x; S.y += a.y;
            f2 c = lq[w][t]; Q.x += c.x; Q.y += c.y;
        }
        partials[blockIdx.x * 128 + 2 * t]       = S.x;
        partials[blockIdx.x * 128 + 2 * t + 1]   = S.y;
        partials[blockIdx.x * 128 + 64 + 2 * t]  = Q.x;
        partials[blockIdx.x * 128 + 65 + 2 * t]  = Q.y;
    }
}

// ---------------- fused dual segment max: 1 node/wave, full 256B-row loads ----------------

__global__ __launch_bounds__(256)
void segmax_dual(const unsigned short* __restrict__ TD, const float* __restrict__ pos,
                 const float* __restrict__ W1, const float* __restrict__ W2,
                 const int* __restrict__ offs, const int* __restrict__ csr,
                 unsigned int* __restrict__ S1o, unsigned int* __restrict__ S2o,
                 float* __restrict__ partials, int N) {
    int t    = threadIdx.x;
    int lane = t & 63;
    int cl   = lane & 31;
    int c0   = cl * 2;
    int wv   = t >> 6;
    int gw   = blockIdx.x * 4 + wv;
    int nw   = gridDim.x * 4;
    const float* Ws = (lane >= 32) ? W2 : W1;
    float wa0 = Ws[c0 * 66 + 64],       wa1 = Ws[c0 * 66 + 65];
    float wb0 = Ws[(c0 + 1) * 66 + 64], wb1 = Ws[(c0 + 1) * 66 + 65];
    f2 sum = {0.f, 0.f}, sq = {0.f, 0.f};
    for (int i = gw; i < N; i += nw) {
        int s0 = offs[i], s1 = offs[i + 1];
        f2 m = { -INFINITY, -INFINITY };
        int e = s0;
        for (; e + 8 <= s1; e += 8) {
            unsigned int v[8];
#pragma unroll
            for (int u = 0; u < 8; ++u)
                v[u] = *(const unsigned int*)&TD[(size_t)csr[e + u] * 128 + lane * 2];
#pragma unroll
            for (int u = 0; u < 8; ++u) {
                f2 f = bf2(v[u]);
                m.x = fmaxf(m.x, f.x);
                m.y = fmaxf(m.y, f.y);
            }
        }
        for (; e + 4 <= s1; e += 4) {
            unsigned int v[4];
#pragma unroll
            for (int u = 0; u < 4; ++u)
                v[u] = *(const unsigned int*)&TD[(size_t)csr[e + u] * 128 + lane * 2];
#pragma unroll
            for (int u = 0; u < 4; ++u) {
                f2 f = bf2(v[u]);
                m.x = fmaxf(m.x, f.x);
                m.y = fmaxf(m.y, f.y);
            }
        }
        for (; e < s1; ++e) {
            f2 f = bf2(*(const unsigned int*)&TD[(size_t)csr[e] * 128 + lane * 2]);
            m.x = fmaxf(m.x, f.x);
            m.y = fmaxf(m.y, f.y);
        }
        float p0 = pos[i * 3], p1 = pos[i * 3 + 1];
        f2 val = {0.f, 0.f};
        if (s1 > s0) {
            val.x = m.x - (p0 * wa0 + p1 * wa1);
            val.y = m.y - (p0 * wb0 + p1 * wb1);
        }
        if (lane < 32) S1o[(size_t)i * 32 + cl] = packbf(val.x, val.y);
        else           S2o[(size_t)i * 32 + cl] = packbf(val.x, val.y);
        sum.x += val.x; sum.y += val.y;
        sq.x  += val.x * val.x; sq.y += val.y * val.y;
    }
    __shared__ f2 ls[4][64];
    __shared__ f2 lq[4][64];
    ls[wv][lane] = sum; lq[wv][lane] = sq;
    __syncthreads();
    if (t < 64) {
        f2 S = {0.f, 0.f}, Q = {0.f, 0.f};
#pragma unroll
        for (int w = 0; w < 4; ++w) {
            f2 a = ls[w][t]; S.x += a.x; S.y += a.y;
            f2 c = lq[w][t]; Q.x += c.x; Q.y += c.y;
        }
        float* P = &partials[blockIdx.x * 256];
        if (t < 32) {
            P[2 * t] = S.x;        P[2 * t + 1] = S.y;
            P[64 + 2 * t] = Q.x;   P[65 + 2 * t] = Q.y;
        } else {
            int u = t - 32;
            P[128 + 2 * u] = S.x;  P[129 + 2 * u] = S.y;
            P[192 + 2 * u] = Q.x;  P[193 + 2 * u] = Q.y;
        }
    }
}

// ---------------- unified heads segment max: cls(0..100) + reg(102..105) + obj(106) ----------------

__global__ __launch_bounds__(256)
void segmax_all(const unsigned short* __restrict__ U, const float* __restrict__ pos,
                const float* __restrict__ Wc, const float* __restrict__ Wr,
                const float* __restrict__ Wo, const int* __restrict__ offs,
                const int* __restrict__ csr, float* __restrict__ out_cls,
                float* __restrict__ out_reg, float* __restrict__ out_obj, int N) {
    int lane = threadIdx.x & 63;
    if (lane >= 54) return;               // no barriers below: safe
    int c0 = lane * 2;
    int wv = threadIdx.x >> 6;
    int gg = blockIdx.x * 4 + wv;
    int ng = gridDim.x * 4;
    float w0x, w0y, w1x, w1y;
    if (lane < 51) {
        w0x = Wc[c0 * 66 + 64]; w0y = Wc[c0 * 66 + 65];
        int c1 = c0 + 1;
        w1x = (c1 < NCLS) ? Wc[c1 * 66 + 64] : 0.f;
        w1y = (c1 < NCLS) ? Wc[c1 * 66 + 65] : 0.f;
    } else if (lane < 53) {
        int rc = (lane - 51) * 2;
        w0x = Wr[rc * 66 + 64];       w0y = Wr[rc * 66 + 65];
        w1x = Wr[(rc + 1) * 66 + 64]; w1y = Wr[(rc + 1) * 66 + 65];
    } else {
        w0x = Wo[64]; w0y = Wo[65]; w1x = 0.f; w1y = 0.f;
    }
    for (int i = gg; i < N; i += ng) {
        int s0 = offs[i], s1 = offs[i + 1];
        f2 m = { -INFINITY, -INFINITY };
        int e = s0;
        for (; e + 8 <= s1; e += 8) {
            unsigned int v[8];
#pragma unroll
            for (int u = 0; u < 8; ++u)
                v[u] = *(const unsigned int*)&U[(size_t)csr[e + u] * LDALL + c0];
#pragma unroll
            for (int u = 0; u < 8; ++u) {
                f2 f = bf2(v[u]);
                m.x = fmaxf(m.x, f.x);
                m.y = fmaxf(m.y, f.y);
            }
        }
        for (; e + 4 <= s1; e += 4) {
            unsigned int v[4];
#pragma unroll
            for (int u = 0; u < 4; ++u)
                v[u] = *(const unsigned int*)&U[(size_t)csr[e + u] * LDALL + c0];
#pragma unroll
            for (int u = 0; u < 4; ++u) {
                f2 f = bf2(v[u]);
                m.x = fmaxf(m.x, f.x);
                m.y = fmaxf(m.y, f.y);
            }
        }
        for (; e < s1; ++e) {
            f2 f0 = bf2(*(const unsigned int*)&U[(size_t)csr[e] * LDALL + c0]);
            m.x = fmaxf(m.x, f0.x);
            m.y = fmaxf(m.y, f0.y);
        }
        float p0 = pos[i * 3], p1 = pos[i * 3 + 1];
        float va = 0.f, vb = 0.f;
        if (s1 > s0) {
            va = m.x - (p0 * w0x + p1 * w0y);
            vb = m.y - (p0 * w1x + p1 * w1y);
        }
        if (lane < 50) {
            out_cls[(size_t)i * NCLS + c0]     = va;
            out_cls[(size_t)i * NCLS + c0 + 1] = vb;
        } else if (lane == 50) {
            out_cls[(size_t)i * NCLS + 100] = va;
        } else if (lane == 51) {
            out_reg[(size_t)i * 4 + 0] = va;
            out_reg[(size_t)i * 4 + 1] = vb;
        } else if (lane == 52) {
            out_reg[(size_t)i * 4 + 2] = va;
            out_reg[(size_t)i * 4 + 3] = vb;
        } else {
            out_obj[i] = va;
        }
    }
}

// ---------------- BN finalize: single (stem) and dual (conv1+conv2) ----------------

__global__ __launch_bounds__(1024)
void bn_finalize(const float* __restrict__ partials, int N,
                 const float* __restrict__ g, const float* __restrict__ be,
                 float* __restrict__ ab) {
    __shared__ double ls[16][64];
    __shared__ double lq[16][64];
    int t = threadIdx.x;
    int c  = t & 63;
    int gr = t >> 6;
    double s = 0.0, q = 0.0;
#pragma unroll 8
    for (int b = 0; b < SEG_BLOCKS / 16; ++b) {
        int blk = gr * (SEG_BLOCKS / 16) + b;
        s += (double)partials[blk * 128 + c];
        q += (double)partials[blk * 128 + 64 + c];
    }
    ls[gr][c] = s; lq[gr][c] = q;
    __syncthreads();
    if (gr == 0) {
        double ss = 0.0, qq = 0.0;
#pragma unroll
        for (int i = 0; i < 16; ++i) { ss += ls[i][c]; qq += lq[i][c]; }
        double invN = 1.0 / (double)N;
        float m = (float)(ss * invN);
        float v = (float)(qq * invN) - m * m;
        float a = g[c] * rsqrtf(v + 1e-5f);
        ab[c]      = a;
        ab[64 + c] = be[c] - m * a;
    }
}

__global__ __launch_bounds__(1024)
void bn_finalize2(const float* __restrict__ partials, int N,
                  const float* __restrict__ g1, const float* __restrict__ be1,
                  const float* __restrict__ g2, const float* __restrict__ be2,
                  float* __restrict__ ab1, float* __restrict__ ab2) {
    __shared__ double L[4][16][64];
    int t = threadIdx.x;
    int c  = t & 63;
    int gr = t >> 6;
    double s1 = 0.0, q1 = 0.0, s2 = 0.0, q2 = 0.0;
#pragma unroll 8
    for (int b = 0; b < SEG_BLOCKS / 16; ++b) {
        const float* P = &partials[(size_t)(gr * (SEG_BLOCKS / 16) + b) * 256];
        s1 += (double)P[c];        q1 += (double)P[64 + c];
        s2 += (double)P[128 + c];  q2 += (double)P[192 + c];
    }
    L[0][gr][c] = s1; L[1][gr][c] = q1; L[2][gr][c] = s2; L[3][gr][c] = q2;
    __syncthreads();
    if (gr == 0) {
        double S1 = 0, Q1 = 0, S2 = 0, Q2 = 0;
#pragma unroll
        for (int i = 0; i < 16; ++i) {
            S1 += L[0][i][c]; Q1 += L[1][i][c];
            S2 += L[2][i][c]; Q2 += L[3][i][c];
        }
        double invN = 1.0 / (double)N;
        float m1 = (float)(S1 * invN);
        float v1 = (float)(Q1 * invN) - m1 * m1;
        float a1 = g1[c] * rsqrtf(v1 + 1e-5f);
        ab1[c]      = a1;
        ab1[64 + c] = be1[c] - m1 * a1;
        float m2 = (float)(S2 * invN);
        float v2 = (float)(Q2 * invN) - m2 * m2;
        float a2 = g2[c] * rsqrtf(v2 + 1e-5f);
        ab2[c]      = a2;
        ab2[64 + c] = be2[c] - m2 * a2;
    }
}

// ---------------- launch ----------------

extern "C" void kernel_launch(void* const* d_in, const int* in_sizes, int n_in,
                              void* d_out, int out_size, void* d_ws, size_t ws_size,
                              hipStream_t stream) {
    const float* x       = (const float*)d_in[0];
    const float* pos     = (const float*)d_in[1];
    const int*   ei      = (const int*)d_in[2];
    const float* W_stem  = (const float*)d_in[3];
    const float* b_stem  = (const float*)d_in[4];
    const float* W_conv1 = (const float*)d_in[5];
    const float* b_conv1 = (const float*)d_in[6];
    const float* W_conv2 = (const float*)d_in[7];
    const float* b_conv2 = (const float*)d_in[8];
    const float* W_regr  = (const float*)d_in[9];
    const float* b_regr  = (const float*)d_in[10];
    const float* W_cls   = (const float*)d_in[11];
    const float* b_cls   = (const float*)d_in[12];
    const float* W_obj   = (const float*)d_in[13];
    const float* b_obj   = (const float*)d_in[14];
    const float* g_stem  = (const float*)d_in[15];
    const float* be_stem = (const float*)d_in[16];
    const float* g_conv1 = (const float*)d_in[17];
    const float* be_conv1= (const float*)d_in[18];
    const float* g_conv2 = (const float*)d_in[19];
    const float* be_conv2= (const float*)d_in[20];

    const int N = in_sizes[0] / 64;
    const int E = in_sizes[2] / 2;
    const int* src = ei;
    const int* dst = ei + E;
    const int K = (N + NPB - 1) / NPB;

    // ---- workspace layout (256B-aligned regions) ----
    char* ws = (char*)d_ws;
    size_t off = 0;
    auto carve = [&](size_t bytes) -> char* {
        char* p = ws + off;
        off += (bytes + 255) & ~(size_t)255;
        return p;
    };
    int*   offs     = (int*)carve((size_t)(N + 1) * 4);
    int*   csr      = (int*)carve((size_t)E * 4);
    unsigned int* staged = (unsigned int*)carve((size_t)E * 4);
    int*   ghist    = (int*)carve((size_t)KMAX * BINB * 4);
    int*   tot      = (int*)carve((size_t)KMAX * 4);
    int*   bstart   = (int*)carve((size_t)(KMAX + 1) * 4);
    unsigned int* S1b = (unsigned int*)carve((size_t)N * 32 * 4);   // bf16 [N][64] as u32[N][32]
    unsigned int* S2b = (unsigned int*)carve((size_t)N * 32 * 4);
    unsigned short* T1 = (unsigned short*)carve((size_t)N * 64 * 2);   // U_stem ; (T1+TD) reused as uAll
    unsigned short* TD = (unsigned short*)carve((size_t)N * 128 * 2);  // U1|U2 interleaved
    float* partials = (float*)carve((size_t)SEG_BLOCKS * 256 * 4);
    float* abS      = (float*)carve(128 * 4);
    float* ab1      = (float*)carve(128 * 4);
    float* ab2      = (float*)carve(128 * 4);
    unsigned short* uAll = T1;   // N*112 bf16 = 22.4MB <= T1+TD (38.4MB, contiguous)

    float* out_cls = (float*)d_out;                       // N x 101
    float* out_reg = out_cls + (size_t)N * NCLS;          // N x 4
    float* out_obj = out_reg + (size_t)N * 4;             // N x 1

    const dim3 blk(256);

    // ---- CSR build ----
    hist_kernel<<<BINB, blk, 0, stream>>>(dst, ghist, E, K);
    scan_hist_kernel<<<K, BINB, 0, stream>>>(ghist, tot, K);
    scan_tot_kernel<<<1, KMAX, 0, stream>>>(tot, bstart, offs, K, N, E);
    scatter_kernel<<<BINB, blk, 0, stream>>>(src, dst, ghist, bstart, staged, E, K);
    build_kernel<<<K, 1024, 0, stream>>>(staged, bstart, offs, csr, N);

    const int ng64 = (N + 63) / 64;

    // ---- stem: f32 x -> T1 (bf16) ----
    gemm_mfma_stem<<<ng64, blk, 0, stream>>>(x, pos, W_stem, b_stem, T1, N);
    segmax64b<<<SEG_BLOCKS, blk, 0, stream>>>(T1, pos, W_stem, offs, csr, S1b, partials, N);
    bn_finalize<<<1, 1024, 0, stream>>>(partials, N, g_stem, be_stem, abS);

    // ---- conv1 + conv2: ONE launch, A staged once -> interleaved TD ----
    gemm_mfma_dual<<<ng64, blk, 0, stream>>>(S1b, pos, W_conv1, b_conv1,
                                             W_conv2, b_conv2, 0, 64, abS, TD, N, 128);
    segmax_dual<<<SEG_BLOCKS, blk, 0, stream>>>(TD, pos, W_conv1, W_conv2, offs, csr,
                                                S1b, S2b, partials, N);
    bn_finalize2<<<1, 1024, 0, stream>>>(partials, N, g_conv1, be_conv1,
                                         g_conv2, be_conv2, ab1, ab2);

    // ---- heads: reg/obj -> uAll cols 102.. ; cls (both column halves, one launch) ----
    gemm_regobj<<<ng64, blk, 0, stream>>>(S1b, pos, W_regr, b_regr,
                                          W_obj, b_obj, ab1, uAll, N);
    gemm_mfma_dual<<<ng64, blk, 0, stream>>>(S2b, pos, W_cls, b_cls,
                                             W_cls, b_cls, 64, NCLS, ab2, uAll, N, LDALL);

    // ---- unified gather for all three outputs ----
    segmax_all<<<SEG_BLOCKS, blk, 0, stream>>>(uAll, pos, W_cls, W_regr, W_obj,
                                               offs, csr, out_cls, out_reg, out_obj, N);
}

// Round 13
// 330.964 us; speedup vs baseline: 1.1443x; 1.0512x over previous
//
#include <hip/hip_runtime.h>
#include <math.h>

#define C64 64
#define CIN 66
#define NCLS 101
#define LDALL 128          // bf16 row stride for unified cls+reg+obj buffer (256B-aligned rows)
#define SEG_BLOCKS 2048    // fixed grid for segmax kernels (deterministic stats slots)
#define NPB 1024           // nodes per bucket (CSR build)
#define KMAX 128           // max buckets
#define BINB 512           // binning blocks

typedef float f4 __attribute__((ext_vector_type(4)));
typedef float f2 __attribute__((ext_vector_type(2)));
typedef short s8 __attribute__((ext_vector_type(8)));   // 8 bf16 = 4 VGPRs (MFMA frag)

// bf16 helpers (RNE pack, shift expand)
__device__ __forceinline__ unsigned short f2bf(float f) {
    unsigned int u = __float_as_uint(f);
    u += 0x7fffu + ((u >> 16) & 1u);
    return (unsigned short)(u >> 16);
}
__device__ __forceinline__ unsigned int packbf(float a, float b) {
    return (unsigned int)f2bf(a) | ((unsigned int)f2bf(b) << 16);
}
__device__ __forceinline__ f2 bf2(unsigned int u) {
    f2 r;
    r.x = __uint_as_float(u << 16);
    r.y = __uint_as_float(u & 0xffff0000u);
    return r;
}

// ---------------- CSR build: two-level bucket sort ----------------

__global__ __launch_bounds__(256)
void hist_kernel(const int* __restrict__ dst, int* __restrict__ ghist, int E, int K) {
    __shared__ int lhist[KMAX];
    int b = blockIdx.x;
    int C = (E + gridDim.x - 1) / gridDim.x;
    int lo = b * C, hi = lo + C; if (hi > E) hi = E;
    for (int k = threadIdx.x; k < K; k += 256) lhist[k] = 0;
    __syncthreads();
    for (int e = lo + threadIdx.x; e < hi; e += 256)
        atomicAdd(&lhist[dst[e] >> 10], 1);
    __syncthreads();
    for (int k = threadIdx.x; k < K; k += 256) ghist[k * BINB + b] = lhist[k];
}

__global__ __launch_bounds__(BINB)
void scan_hist_kernel(int* __restrict__ ghist, int* __restrict__ tot, int K) {
    __shared__ int buf[2][BINB];
    int k = blockIdx.x;
    int t = threadIdx.x;
    int v = ghist[k * BINB + t];
    buf[0][t] = v;
    __syncthreads();
    int cur = 0;
    for (int off = 1; off < BINB; off <<= 1) {
        int nv = buf[cur][t];
        if (t >= off) nv += buf[cur][t - off];
        buf[cur ^ 1][t] = nv;
        cur ^= 1;
        __syncthreads();
    }
    ghist[k * BINB + t] = buf[cur][t] - v;
    if (t == BINB - 1) tot[k] = buf[cur][t];
}

__global__ __launch_bounds__(KMAX)
void scan_tot_kernel(const int* __restrict__ tot, int* __restrict__ bstart,
                     int* __restrict__ offs, int K, int N, int E) {
    __shared__ int buf[2][KMAX];
    int t = threadIdx.x;
    int v = (t < K) ? tot[t] : 0;
    buf[0][t] = v;
    __syncthreads();
    int cur = 0;
    for (int off = 1; off < KMAX; off <<= 1) {
        int nv = buf[cur][t];
        if (t >= off) nv += buf[cur][t - off];
        buf[cur ^ 1][t] = nv;
        cur ^= 1;
        __syncthreads();
    }
    if (t < K) bstart[t] = buf[cur][t] - v;
    if (t == 0) { bstart[K] = E; offs[N] = E; }
}

__global__ __launch_bounds__(256)
void scatter_kernel(const int* __restrict__ src, const int* __restrict__ dst,
                    const int* __restrict__ ghist, const int* __restrict__ bstart,
                    unsigned int* __restrict__ staged, int E, int K) {
    __shared__ int lbase[KMAX];
    int b = blockIdx.x;
    int C = (E + gridDim.x - 1) / gridDim.x;
    int lo = b * C, hi = lo + C; if (hi > E) hi = E;
    for (int k = threadIdx.x; k < K; k += 256)
        lbase[k] = bstart[k] + ghist[k * BINB + b];
    __syncthreads();
    for (int e = lo + threadIdx.x; e < hi; e += 256) {
        int d = dst[e];
        int k = d >> 10;
        int p = atomicAdd(&lbase[k], 1);
        staged[p] = (unsigned int)src[e] | ((unsigned int)(d & (NPB - 1)) << 17);
    }
}

__global__ __launch_bounds__(1024)
void build_kernel(const unsigned int* __restrict__ staged, const int* __restrict__ bstart,
                  int* __restrict__ offs, int* __restrict__ csr, int N) {
    __shared__ int cnt[1024];
    __shared__ int buf[1024];
    int k = blockIdx.x;
    int t = threadIdx.x;
    int e0 = bstart[k], e1 = bstart[k + 1];
    cnt[t] = 0;
    __syncthreads();
    for (int p = e0 + t; p < e1; p += 1024)
        atomicAdd(&cnt[staged[p] >> 17], 1);
    __syncthreads();
    int myc = cnt[t];
    int* a = cnt; int* bb = buf;
    for (int off = 1; off < 1024; off <<= 1) {
        int v = a[t];
        if (t >= off) v += a[t - off];
        bb[t] = v;
        __syncthreads();
        int* tmp = a; a = bb; bb = tmp;
    }
    int excl = a[t] - myc;
    int node = k * NPB + t;
    if (node < N) offs[node] = e0 + excl;
    bb[t] = excl;
    __syncthreads();
    for (int p = e0 + t; p < e1; p += 1024) {
        unsigned int v = staged[p];
        int n = v >> 17;
        int q = atomicAdd(&bb[n], 1);
        csr[e0 + q] = (int)(v & 0x1FFFFu);
    }
}

// ---------------- stem MFMA GEMM (f32 input, single W, 64 cols) ----------------

__global__ __launch_bounds__(256)
void gemm_mfma_stem(const float* __restrict__ feat, const float* __restrict__ pos,
                    const float* __restrict__ W, const float* __restrict__ bi,
                    unsigned short* __restrict__ U, int N) {
    __shared__ __attribute__((aligned(16))) unsigned short As[64][104];
    __shared__ __attribute__((aligned(16))) unsigned short Bs[64][104];
    int row0 = blockIdx.x * 64;
    int tid  = threadIdx.x;

    for (int idx = tid; idx < 64 * 52; idx += 256) {
        int r = idx / 52, k2 = idx - r * 52;
        int grow = row0 + r;
        unsigned int pack = 0;
        if (grow < N && k2 <= 32) {
            float v0, v1;
            if (k2 < 32) {
                f2 v = *(const f2*)&feat[(size_t)grow * 64 + k2 * 2];
                v0 = v.x; v1 = v.y;
            } else {
                v0 = pos[(size_t)grow * 3 + 0];
                v1 = pos[(size_t)grow * 3 + 1];
            }
            pack = packbf(v0, v1);
        }
        *(unsigned int*)&As[r][k2 * 2] = pack;
    }
    for (int idx = tid; idx < 64 * 52; idx += 256) {
        int c = idx / 52, k2 = idx - c * 52;
        unsigned int pack = 0;
        if (k2 <= 32) {
            f2 v = *(const f2*)&W[(size_t)c * 66 + k2 * 2];
            pack = packbf(v.x, v.y);
        }
        *(unsigned int*)&Bs[c][k2 * 2] = pack;
    }
    __syncthreads();

    int lane = tid & 63;
    int wv   = tid >> 6;
    int l16  = lane & 15;
    int kg   = lane >> 4;
    int wr   = wv * 16;

    f4 acc[4];
#pragma unroll
    for (int t = 0; t < 4; ++t) acc[t] = (f4)(0.f);

#pragma unroll
    for (int s = 0; s < 3; ++s) {
        s8 a = *(const s8*)&As[wr + l16][s * 32 + kg * 8];
#pragma unroll
        for (int t = 0; t < 4; ++t) {
            s8 b = *(const s8*)&Bs[t * 16 + l16][s * 32 + kg * 8];
            acc[t] = __builtin_amdgcn_mfma_f32_16x16x32_bf16(a, b, acc[t], 0, 0, 0);
        }
    }

#pragma unroll
    for (int t = 0; t < 4; ++t) {
        int gc = t * 16 + l16;
        float bv = bi[gc];
#pragma unroll
        for (int r = 0; r < 4; ++r) {
            int grow = row0 + wr + kg * 4 + r;
            if (grow < N)
                U[(size_t)grow * 64 + gc] = f2bf(acc[t][r] + bv);
        }
    }
}

// ---------------- dual MFMA GEMM: one A-stage, 128 output cols ----------------

__global__ __launch_bounds__(256)
void gemm_mfma_dual(const unsigned int* __restrict__ sb, const float* __restrict__ pos,
                    const float* __restrict__ Wa, const float* __restrict__ ba,
                    const float* __restrict__ Wb, const float* __restrict__ bb,
                    int wbaseB, int WROWSB, const float* __restrict__ ab,
                    unsigned short* __restrict__ U, int N, int ldU) {
    __shared__ __attribute__((aligned(16))) unsigned short As[64][104];
    __shared__ __attribute__((aligned(16))) unsigned short Bs[128][104];
    int row0 = blockIdx.x * 64;
    int tid  = threadIdx.x;

    for (int idx = tid; idx < 64 * 52; idx += 256) {
        int r = idx / 52, k2 = idx - r * 52;
        int grow = row0 + r;
        unsigned int pack = 0;
        if (grow < N && k2 <= 32) {
            float v0, v1;
            if (k2 < 32) {
                f2 v = bf2(sb[(size_t)grow * 32 + k2]);
                int k = k2 * 2;
                v0 = fmaxf(0.f, v.x * ab[k] + ab[64 + k]);
                v1 = fmaxf(0.f, v.y * ab[k + 1] + ab[64 + k + 1]);
            } else {
                v0 = pos[(size_t)grow * 3 + 0];
                v1 = pos[(size_t)grow * 3 + 1];
            }
            pack = packbf(v0, v1);
        }
        *(unsigned int*)&As[r][k2 * 2] = pack;
    }
    for (int idx = tid; idx < 128 * 52; idx += 256) {
        int c = idx / 52, k2 = idx - c * 52;
        unsigned int pack = 0;
        const float* W = (c < 64) ? Wa : Wb;
        int wrow = (c < 64) ? c : (wbaseB + (c - 64));
        bool valid = (c < 64) ? true : (wrow < WROWSB);
        if (valid && k2 <= 32) {
            f2 v = *(const f2*)&W[(size_t)wrow * 66 + k2 * 2];
            pack = packbf(v.x, v.y);
        }
        *(unsigned int*)&Bs[c][k2 * 2] = pack;
    }
    __syncthreads();

    int lane = tid & 63;
    int wv   = tid >> 6;
    int l16  = lane & 15;
    int kg   = lane >> 4;
    int wr   = wv * 16;

    f4 acc[8];
#pragma unroll
    for (int t = 0; t < 8; ++t) acc[t] = (f4)(0.f);

#pragma unroll
    for (int s = 0; s < 3; ++s) {
        s8 a = *(const s8*)&As[wr + l16][s * 32 + kg * 8];
#pragma unroll
        for (int t = 0; t < 8; ++t) {
            s8 b = *(const s8*)&Bs[t * 16 + l16][s * 32 + kg * 8];
            acc[t] = __builtin_amdgcn_mfma_f32_16x16x32_bf16(a, b, acc[t], 0, 0, 0);
        }
    }

#pragma unroll
    for (int t = 0; t < 8; ++t) {
        int cl = t * 16 + l16;
        float bv;
        bool valid;
        if (cl < 64) { bv = ba[cl]; valid = true; }
        else {
            int wrow = wbaseB + (cl - 64);
            valid = wrow < WROWSB;
            bv = valid ? bb[wrow] : 0.f;
        }
        if (!valid) continue;
#pragma unroll
        for (int r = 0; r < 4; ++r) {
            int grow = row0 + wr + kg * 4 + r;
            if (grow < N)
                U[(size_t)grow * ldU + cl] = f2bf(acc[t][r] + bv);
        }
    }
}

// ---------------- reg(4)+obj(1) heads (bf16 in, bf16 out -> uAll cols 102..106) ----------------

__global__ __launch_bounds__(256)
void gemm_regobj(const unsigned int* __restrict__ sb, const float* __restrict__ pos,
                 const float* __restrict__ Wr, const float* __restrict__ br,
                 const float* __restrict__ Wo, const float* __restrict__ bo,
                 const float* __restrict__ ab, unsigned short* __restrict__ uAll, int N) {
    __shared__ __attribute__((aligned(16))) float As[64][68];
    __shared__ float Wt[66][5];
    int row0 = blockIdx.x * 64;
    int tid  = threadIdx.x;
    for (int idx = tid; idx < 64 * 33; idx += 256) {
        int r = idx / 33, k2 = idx - r * 33;
        int grow = row0 + r;
        float v0 = 0.f, v1 = 0.f;
        if (grow < N) {
            if (k2 < 32) {
                f2 v = bf2(sb[(size_t)grow * 32 + k2]);
                int k = k2 * 2;
                v0 = fmaxf(0.f, v.x * ab[k] + ab[64 + k]);
                v1 = fmaxf(0.f, v.y * ab[k + 1] + ab[64 + k + 1]);
            } else {
                v0 = pos[(size_t)grow * 3 + 0];
                v1 = pos[(size_t)grow * 3 + 1];
            }
        }
        As[r][k2 * 2]     = v0;
        As[r][k2 * 2 + 1] = v1;
    }
    for (int idx = tid; idx < 66 * 5; idx += 256) {
        int c = idx / 66, k = idx - c * 66;
        Wt[k][c] = (c < 4) ? Wr[(size_t)c * 66 + k] : Wo[k];
    }
    __syncthreads();
    int r  = tid & 63;
    int cs = tid >> 6;     // 0..3
    int grow = row0 + r;
    if (grow >= N) return;
    float acc = 0.f, acco = 0.f;
    for (int k = 0; k < 66; ++k) {
        float a = As[r][k];
        acc += a * Wt[k][cs];
        if (cs == 0) acco += a * Wt[k][4];
    }
    uAll[(size_t)grow * LDALL + 102 + cs] = f2bf(acc + br[cs]);
    if (cs == 0) uAll[(size_t)grow * LDALL + 106] = f2bf(acco + bo[0]);
}

// ---------------- segment max, 64ch bf16 (stem): 1 node/wave, clamped 8-edge blocks ----------------

__global__ __launch_bounds__(256)
void segmax64b(const unsigned short* __restrict__ U, const float* __restrict__ pos,
               const float* __restrict__ W, const int* __restrict__ offs,
               const int* __restrict__ csr, unsigned int* __restrict__ outb,
               float* __restrict__ partials, int N) {
    int t    = threadIdx.x;
    int lane = t & 63;
    int h    = lane >> 5;       // edge parity handled by this half-wave
    int cl   = lane & 31;
    int c0   = cl * 2;
    int wv   = t >> 6;
    int gw   = blockIdx.x * 4 + wv;
    int nw   = gridDim.x * 4;
    float wa0 = W[c0 * 66 + 64],       wa1 = W[c0 * 66 + 65];
    float wb0 = W[(c0 + 1) * 66 + 64], wb1 = W[(c0 + 1) * 66 + 65];
    f2 sum = {0.f, 0.f}, sq = {0.f, 0.f};
    for (int i = gw; i < N; i += nw) {
        int s0 = offs[i], s1 = offs[i + 1];
        f2 m = { -INFINITY, -INFINITY };
        // clamped 8-edge blocks: duplicated last-edge loads are idempotent under max
        for (int e = s0; e < s1; e += 8) {
            unsigned int v[4];
#pragma unroll
            for (int u = 0; u < 4; ++u) {
                int ee = e + 2 * u + h;
                if (ee > s1 - 1) ee = s1 - 1;
                v[u] = *(const unsigned int*)&U[(size_t)csr[ee] * 64 + c0];
            }
#pragma unroll
            for (int u = 0; u < 4; ++u) {
                f2 f = bf2(v[u]);
                m.x = fmaxf(m.x, f.x);
                m.y = fmaxf(m.y, f.y);
            }
        }
        m.x = fmaxf(m.x, __shfl_xor(m.x, 32));
        m.y = fmaxf(m.y, __shfl_xor(m.y, 32));
        if (h == 0) {
            float p0 = pos[i * 3], p1 = pos[i * 3 + 1];
            f2 val = {0.f, 0.f};
            if (s1 > s0) {
                val.x = m.x - (p0 * wa0 + p1 * wa1);
                val.y = m.y - (p0 * wb0 + p1 * wb1);
            }
            outb[(size_t)i * 32 + cl] = packbf(val.x, val.y);
            sum.x += val.x; sum.y += val.y;
            sq.x  += val.x * val.x; sq.y += val.y * val.y;
        }
    }
    __shared__ f2 ls[4][32];
    __shared__ f2 lq[4][32];
    if (h == 0) { ls[wv][cl] = sum; lq[wv][cl] = sq; }
    __syncthreads();
    if (t < 32) {
        f2 S = {0.f, 0.f}, Q = {0.f, 0.f};
#pragma unroll
        for (int w = 0; w < 4; ++w) {
            f2 a = ls[w][t]; S.x += a.x; S.y += a.y;
            f2 c = lq[w][t]; Q.x += c.x; Q.y += c.y;
        }
        partials[blockIdx.x * 128 + 2 * t]       = S.x;
        partials[blockIdx.x * 128 + 2 * t + 1]   = S.y;
        partials[blockIdx.x * 128 + 64 + 2 * t]  = Q.x;
        partials[blockIdx.x * 128 + 65 + 2 * t]  = Q.y;
    }
}

// ---------------- fused dual segment max: 1 node/wave, clamped 8-edge blocks ----------------

__global__ __launch_bounds__(256)
void segmax_dual(const unsigned short* __restrict__ TD, const float* __restrict__ pos,
                 const float* __restrict__ W1, const float* __restrict__ W2,
                 const int* __restrict__ offs, const int* __restrict__ csr,
                 unsigned int* __restrict__ S1o, unsigned int* __restrict__ S2o,
                 float* __restrict__ partials, int N) {
    int t    = threadIdx.x;
    int lane = t & 63;
    int cl   = lane & 31;
    int c0   = cl * 2;
    int wv   = t >> 6;
    int gw   = blockIdx.x * 4 + wv;
    int nw   = gridDim.x * 4;
    const float* Ws = (lane >= 32) ? W2 : W1;
    float wa0 = Ws[c0 * 66 + 64],       wa1 = Ws[c0 * 66 + 65];
    float wb0 = Ws[(c0 + 1) * 66 + 64], wb1 = Ws[(c0 + 1) * 66 + 65];
    f2 sum = {0.f, 0.f}, sq = {0.f, 0.f};
    for (int i = gw; i < N; i += nw) {
        int s0 = offs[i], s1 = offs[i + 1];
        f2 m = { -INFINITY, -INFINITY };
        for (int e = s0; e < s1; e += 8) {
            unsigned int v[8];
#pragma unroll
            for (int u = 0; u < 8; ++u) {
                int ee = e + u;
                if (ee > s1 - 1) ee = s1 - 1;
                v[u] = *(const unsigned int*)&TD[(size_t)csr[ee] * 128 + lane * 2];
            }
#pragma unroll
            for (int u = 0; u < 8; ++u) {
                f2 f = bf2(v[u]);
                m.x = fmaxf(m.x, f.x);
                m.y = fmaxf(m.y, f.y);
            }
        }
        float p0 = pos[i * 3], p1 = pos[i * 3 + 1];
        f2 val = {0.f, 0.f};
        if (s1 > s0) {
            val.x = m.x - (p0 * wa0 + p1 * wa1);
            val.y = m.y - (p0 * wb0 + p1 * wb1);
        }
        if (lane < 32) S1o[(size_t)i * 32 + cl] = packbf(val.x, val.y);
        else           S2o[(size_t)i * 32 + cl] = packbf(val.x, val.y);
        sum.x += val.x; sum.y += val.y;
        sq.x  += val.x * val.x; sq.y += val.y * val.y;
    }
    __shared__ f2 ls[4][64];
    __shared__ f2 lq[4][64];
    ls[wv][lane] = sum; lq[wv][lane] = sq;
    __syncthreads();
    if (t < 64) {
        f2 S = {0.f, 0.f}, Q = {0.f, 0.f};
#pragma unroll
        for (int w = 0; w < 4; ++w) {
            f2 a = ls[w][t]; S.x += a.x; S.y += a.y;
            f2 c = lq[w][t]; Q.x += c.x; Q.y += c.y;
        }
        float* P = &partials[blockIdx.x * 256];
        if (t < 32) {
            P[2 * t] = S.x;        P[2 * t + 1] = S.y;
            P[64 + 2 * t] = Q.x;   P[65 + 2 * t] = Q.y;
        } else {
            int u = t - 32;
            P[128 + 2 * u] = S.x;  P[129 + 2 * u] = S.y;
            P[192 + 2 * u] = Q.x;  P[193 + 2 * u] = Q.y;
        }
    }
}

// ---------------- unified heads segment max: cls(0..100) + reg(102..105) + obj(106) ----------------

__global__ __launch_bounds__(256)
void segmax_all(const unsigned short* __restrict__ U, const float* __restrict__ pos,
                const float* __restrict__ Wc, const float* __restrict__ Wr,
                const float* __restrict__ Wo, const int* __restrict__ offs,
                const int* __restrict__ csr, float* __restrict__ out_cls,
                float* __restrict__ out_reg, float* __restrict__ out_obj, int N) {
    int lane = threadIdx.x & 63;
    if (lane >= 54) return;               // no barriers below: safe
    int c0 = lane * 2;
    int wv = threadIdx.x >> 6;
    int gg = blockIdx.x * 4 + wv;
    int ng = gridDim.x * 4;
    float w0x, w0y, w1x, w1y;
    if (lane < 51) {
        w0x = Wc[c0 * 66 + 64]; w0y = Wc[c0 * 66 + 65];
        int c1 = c0 + 1;
        w1x = (c1 < NCLS) ? Wc[c1 * 66 + 64] : 0.f;
        w1y = (c1 < NCLS) ? Wc[c1 * 66 + 65] : 0.f;
    } else if (lane < 53) {
        int rc = (lane - 51) * 2;
        w0x = Wr[rc * 66 + 64];       w0y = Wr[rc * 66 + 65];
        w1x = Wr[(rc + 1) * 66 + 64]; w1y = Wr[(rc + 1) * 66 + 65];
    } else {
        w0x = Wo[64]; w0y = Wo[65]; w1x = 0.f; w1y = 0.f;
    }
    for (int i = gg; i < N; i += ng) {
        int s0 = offs[i], s1 = offs[i + 1];
        f2 m = { -INFINITY, -INFINITY };
        for (int e = s0; e < s1; e += 8) {
            unsigned int v[8];
#pragma unroll
            for (int u = 0; u < 8; ++u) {
                int ee = e + u;
                if (ee > s1 - 1) ee = s1 - 1;
                v[u] = *(const unsigned int*)&U[(size_t)csr[ee] * LDALL + c0];
            }
#pragma unroll
            for (int u = 0; u < 8; ++u) {
                f2 f = bf2(v[u]);
                m.x = fmaxf(m.x, f.x);
                m.y = fmaxf(m.y, f.y);
            }
        }
        float p0 = pos[i * 3], p1 = pos[i * 3 + 1];
        float va = 0.f, vb = 0.f;
        if (s1 > s0) {
            va = m.x - (p0 * w0x + p1 * w0y);
            vb = m.y - (p0 * w1x + p1 * w1y);
        }
        if (lane < 50) {
            out_cls[(size_t)i * NCLS + c0]     = va;
            out_cls[(size_t)i * NCLS + c0 + 1] = vb;
        } else if (lane == 50) {
            out_cls[(size_t)i * NCLS + 100] = va;
        } else if (lane == 51) {
            out_reg[(size_t)i * 4 + 0] = va;
            out_reg[(size_t)i * 4 + 1] = vb;
        } else if (lane == 52) {
            out_reg[(size_t)i * 4 + 2] = va;
            out_reg[(size_t)i * 4 + 3] = vb;
        } else {
            out_obj[i] = va;
        }
    }
}

// ---------------- BN finalize: single (stem) and dual (conv1+conv2) ----------------

__global__ __launch_bounds__(1024)
void bn_finalize(const float* __restrict__ partials, int N,
                 const float* __restrict__ g, const float* __restrict__ be,
                 float* __restrict__ ab) {
    __shared__ double ls[16][64];
    __shared__ double lq[16][64];
    int t = threadIdx.x;
    int c  = t & 63;
    int gr = t >> 6;
    double s = 0.0, q = 0.0;
#pragma unroll 8
    for (int b = 0; b < SEG_BLOCKS / 16; ++b) {
        int blk = gr * (SEG_BLOCKS / 16) + b;
        s += (double)partials[blk * 128 + c];
        q += (double)partials[blk * 128 + 64 + c];
    }
    ls[gr][c] = s; lq[gr][c] = q;
    __syncthreads();
    if (gr == 0) {
        double ss = 0.0, qq = 0.0;
#pragma unroll
        for (int i = 0; i < 16; ++i) { ss += ls[i][c]; qq += lq[i][c]; }
        double invN = 1.0 / (double)N;
        float m = (float)(ss * invN);
        float v = (float)(qq * invN) - m * m;
        float a = g[c] * rsqrtf(v + 1e-5f);
        ab[c]      = a;
        ab[64 + c] = be[c] - m * a;
    }
}

__global__ __launch_bounds__(1024)
void bn_finalize2(const float* __restrict__ partials, int N,
                  const float* __restrict__ g1, const float* __restrict__ be1,
                  const float* __restrict__ g2, const float* __restrict__ be2,
                  float* __restrict__ ab1, float* __restrict__ ab2) {
    __shared__ double L[4][16][64];
    int t = threadIdx.x;
    int c  = t & 63;
    int gr = t >> 6;
    double s1 = 0.0, q1 = 0.0, s2 = 0.0, q2 = 0.0;
#pragma unroll 8
    for (int b = 0; b < SEG_BLOCKS / 16; ++b) {
        const float* P = &partials[(size_t)(gr * (SEG_BLOCKS / 16) + b) * 256];
        s1 += (double)P[c];        q1 += (double)P[64 + c];
        s2 += (double)P[128 + c];  q2 += (double)P[192 + c];
    }
    L[0][gr][c] = s1; L[1][gr][c] = q1; L[2][gr][c] = s2; L[3][gr][c] = q2;
    __syncthreads();
    if (gr == 0) {
        double S1 = 0, Q1 = 0, S2 = 0, Q2 = 0;
#pragma unroll
        for (int i = 0; i < 16; ++i) {
            S1 += L[0][i][c]; Q1 += L[1][i][c];
            S2 += L[2][i][c]; Q2 += L[3][i][c];
        }
        double invN = 1.0 / (double)N;
        float m1 = (float)(S1 * invN);
        float v1 = (float)(Q1 * invN) - m1 * m1;
        float a1 = g1[c] * rsqrtf(v1 + 1e-5f);
        ab1[c]      = a1;
        ab1[64 + c] = be1[c] - m1 * a1;
        float m2 = (float)(S2 * invN);
        float v2 = (float)(Q2 * invN) - m2 * m2;
        float a2 = g2[c] * rsqrtf(v2 + 1e-5f);
        ab2[c]      = a2;
        ab2[64 + c] = be2[c] - m2 * a2;
    }
}

// ---------------- launch ----------------

extern "C" void kernel_launch(void* const* d_in, const int* in_sizes, int n_in,
                              void* d_out, int out_size, void* d_ws, size_t ws_size,
                              hipStream_t stream) {
    const float* x       = (const float*)d_in[0];
    const float* pos     = (const float*)d_in[1];
    const int*   ei      = (const int*)d_in[2];
    const float* W_stem  = (const float*)d_in[3];
    const float* b_stem  = (const float*)d_in[4];
    const float* W_conv1 = (const float*)d_in[5];
    const float* b_conv1 = (const float*)d_in[6];
    const float* W_conv2 = (const float*)d_in[7];
    const float* b_conv2 = (const float*)d_in[8];
    const float* W_regr  = (const float*)d_in[9];
    const float* b_regr  = (const float*)d_in[10];
    const float* W_cls   = (const float*)d_in[11];
    const float* b_cls   = (const float*)d_in[12];
    const float* W_obj   = (const float*)d_in[13];
    const float* b_obj   = (const float*)d_in[14];
    const float* g_stem  = (const float*)d_in[15];
    const float* be_stem = (const float*)d_in[16];
    const float* g_conv1 = (const float*)d_in[17];
    const float* be_conv1= (const float*)d_in[18];
    const float* g_conv2 = (const float*)d_in[19];
    const float* be_conv2= (const float*)d_in[20];

    const int N = in_sizes[0] / 64;
    const int E = in_sizes[2] / 2;
    const int* src = ei;
    const int* dst = ei + E;
    const int K = (N + NPB - 1) / NPB;

    // ---- workspace layout (256B-aligned regions) ----
    char* ws = (char*)d_ws;
    size_t off = 0;
    auto carve = [&](size_t bytes) -> char* {
        char* p = ws + off;
        off += (bytes + 255) & ~(size_t)255;
        return p;
    };
    int*   offs     = (int*)carve((size_t)(N + 1) * 4);
    int*   csr      = (int*)carve((size_t)E * 4);
    unsigned int* staged = (unsigned int*)carve((size_t)E * 4);
    int*   ghist    = (int*)carve((size_t)KMAX * BINB * 4);
    int*   tot      = (int*)carve((size_t)KMAX * 4);
    int*   bstart   = (int*)carve((size_t)(KMAX + 1) * 4);
    unsigned int* S1b = (unsigned int*)carve((size_t)N * 32 * 4);   // bf16 [N][64] as u32[N][32]
    unsigned int* S2b = (unsigned int*)carve((size_t)N * 32 * 4);
    unsigned short* T1 = (unsigned short*)carve((size_t)N * 64 * 2);   // U_stem ; (T1+TD) reused as uAll
    unsigned short* TD = (unsigned short*)carve((size_t)N * 128 * 2);  // U1|U2 interleaved
    float* partials = (float*)carve((size_t)SEG_BLOCKS * 256 * 4);
    float* abS      = (float*)carve(128 * 4);
    float* ab1      = (float*)carve(128 * 4);
    float* ab2      = (float*)carve(128 * 4);
    unsigned short* uAll = T1;   // N*128 bf16 = 25.6MB <= T1+TD (38.4MB, contiguous)

    float* out_cls = (float*)d_out;                       // N x 101
    float* out_reg = out_cls + (size_t)N * NCLS;          // N x 4
    float* out_obj = out_reg + (size_t)N * 4;             // N x 1

    const dim3 blk(256);

    // ---- CSR build ----
    hist_kernel<<<BINB, blk, 0, stream>>>(dst, ghist, E, K);
    scan_hist_kernel<<<K, BINB, 0, stream>>>(ghist, tot, K);
    scan_tot_kernel<<<1, KMAX, 0, stream>>>(tot, bstart, offs, K, N, E);
    scatter_kernel<<<BINB, blk, 0, stream>>>(src, dst, ghist, bstart, staged, E, K);
    build_kernel<<<K, 1024, 0, stream>>>(staged, bstart, offs, csr, N);

    const int ng64 = (N + 63) / 64;

    // ---- stem: f32 x -> T1 (bf16) ----
    gemm_mfma_stem<<<ng64, blk, 0, stream>>>(x, pos, W_stem, b_stem, T1, N);
    segmax64b<<<SEG_BLOCKS, blk, 0, stream>>>(T1, pos, W_stem, offs, csr, S1b, partials, N);
    bn_finalize<<<1, 1024, 0, stream>>>(partials, N, g_stem, be_stem, abS);

    // ---- conv1 + conv2: ONE launch, A staged once -> interleaved TD ----
    gemm_mfma_dual<<<ng64, blk, 0, stream>>>(S1b, pos, W_conv1, b_conv1,
                                             W_conv2, b_conv2, 0, 64, abS, TD, N, 128);
    segmax_dual<<<SEG_BLOCKS, blk, 0, stream>>>(TD, pos, W_conv1, W_conv2, offs, csr,
                                                S1b, S2b, partials, N);
    bn_finalize2<<<1, 1024, 0, stream>>>(partials, N, g_conv1, be_conv1,
                                         g_conv2, be_conv2, ab1, ab2);

    // ---- heads: reg/obj -> uAll cols 102.. ; cls (both column halves, one launch) ----
    gemm_regobj<<<ng64, blk, 0, stream>>>(S1b, pos, W_regr, b_regr,
                                          W_obj, b_obj, ab1, uAll, N);
    gemm_mfma_dual<<<ng64, blk, 0, stream>>>(S2b, pos, W_cls, b_cls,
                                             W_cls, b_cls, 64, NCLS, ab2, uAll, N, LDALL);

    // ---- unified gather for all three outputs ----
    segmax_all<<<SEG_BLOCKS, blk, 0, stream>>>(uAll, pos, W_cls, W_regr, W_obj,
                                               offs, csr, out_cls, out_reg, out_obj, N);
}

// Round 14
// 309.935 us; speedup vs baseline: 1.2219x; 1.0679x over previous
//
#include <hip/hip_runtime.h>
#include <math.h>

#define C64 64
#define CIN 66
#define NCLS 101
#define LDALL 128          // bf16 row stride for unified cls+reg+obj buffer (256B-aligned rows)
#define SEG_BLOCKS 2048    // fixed grid for segmax kernels (deterministic stats slots)
#define NPB 1024           // nodes per bucket (CSR build)
#define KMAX 128           // max buckets
#define BINB 512           // binning blocks

typedef float f4 __attribute__((ext_vector_type(4)));
typedef float f2 __attribute__((ext_vector_type(2)));
typedef short s8 __attribute__((ext_vector_type(8)));            // 8 bf16 = 4 VGPRs (MFMA frag)
typedef unsigned int u32x4 __attribute__((ext_vector_type(4)));  // 16B copy unit

// bf16 helpers (RNE pack, shift expand)
__device__ __forceinline__ unsigned short f2bf(float f) {
    unsigned int u = __float_as_uint(f);
    u += 0x7fffu + ((u >> 16) & 1u);
    return (unsigned short)(u >> 16);
}
__device__ __forceinline__ unsigned int packbf(float a, float b) {
    return (unsigned int)f2bf(a) | ((unsigned int)f2bf(b) << 16);
}
__device__ __forceinline__ f2 bf2(unsigned int u) {
    f2 r;
    r.x = __uint_as_float(u << 16);
    r.y = __uint_as_float(u & 0xffff0000u);
    return r;
}

// ---------------- weight image prep (once): bf16-packed padded LDS images ----------------
// img layout (u32, 52 per row = 104 bf16): rows 0..63 stem W; 64..191 conv W1|W2;
// 192..319 cls W rows 0..127 (valid <101). k2==32 holds cols 64,65; k2>32 zero.

__global__ __launch_bounds__(256)
void wprep_kernel(const float* __restrict__ Ws, const float* __restrict__ W1,
                  const float* __restrict__ W2, const float* __restrict__ Wc,
                  unsigned int* __restrict__ img) {
    int idx = blockIdx.x * 256 + threadIdx.x;
    if (idx >= 320 * 52) return;
    int row = idx / 52, k2 = idx - row * 52;
    const float* W; int wrow; bool valid = true;
    if (row < 64)       { W = Ws; wrow = row; }
    else if (row < 192) { int r = row - 64; W = (r < 64) ? W1 : W2; wrow = (r < 64) ? r : r - 64; }
    else                { int r = row - 192; W = Wc; wrow = r; valid = (r < NCLS); }
    unsigned int pack = 0;
    if (valid && k2 <= 32) {
        f2 v = *(const f2*)&W[(size_t)wrow * 66 + k2 * 2];
        pack = packbf(v.x, v.y);
    }
    img[idx] = pack;
}

// ---------------- CSR build: two-level bucket sort ----------------

__global__ __launch_bounds__(256)
void hist_kernel(const int* __restrict__ dst, int* __restrict__ ghist, int E, int K) {
    __shared__ int lhist[KMAX];
    int b = blockIdx.x;
    int C = (E + gridDim.x - 1) / gridDim.x;
    int lo = b * C, hi = lo + C; if (hi > E) hi = E;
    for (int k = threadIdx.x; k < K; k += 256) lhist[k] = 0;
    __syncthreads();
    for (int e = lo + threadIdx.x; e < hi; e += 256)
        atomicAdd(&lhist[dst[e] >> 10], 1);
    __syncthreads();
    for (int k = threadIdx.x; k < K; k += 256) ghist[k * BINB + b] = lhist[k];
}

__global__ __launch_bounds__(BINB)
void scan_hist_kernel(int* __restrict__ ghist, int* __restrict__ tot, int K) {
    __shared__ int buf[2][BINB];
    int k = blockIdx.x;
    int t = threadIdx.x;
    int v = ghist[k * BINB + t];
    buf[0][t] = v;
    __syncthreads();
    int cur = 0;
    for (int off = 1; off < BINB; off <<= 1) {
        int nv = buf[cur][t];
        if (t >= off) nv += buf[cur][t - off];
        buf[cur ^ 1][t] = nv;
        cur ^= 1;
        __syncthreads();
    }
    ghist[k * BINB + t] = buf[cur][t] - v;
    if (t == BINB - 1) tot[k] = buf[cur][t];
}

__global__ __launch_bounds__(KMAX)
void scan_tot_kernel(const int* __restrict__ tot, int* __restrict__ bstart,
                     int* __restrict__ offs, int K, int N, int E) {
    __shared__ int buf[2][KMAX];
    int t = threadIdx.x;
    int v = (t < K) ? tot[t] : 0;
    buf[0][t] = v;
    __syncthreads();
    int cur = 0;
    for (int off = 1; off < KMAX; off <<= 1) {
        int nv = buf[cur][t];
        if (t >= off) nv += buf[cur][t - off];
        buf[cur ^ 1][t] = nv;
        cur ^= 1;
        __syncthreads();
    }
    if (t < K) bstart[t] = buf[cur][t] - v;
    if (t == 0) { bstart[K] = E; offs[N] = E; }
}

__global__ __launch_bounds__(256)
void scatter_kernel(const int* __restrict__ src, const int* __restrict__ dst,
                    const int* __restrict__ ghist, const int* __restrict__ bstart,
                    unsigned int* __restrict__ staged, int E, int K) {
    __shared__ int lbase[KMAX];
    int b = blockIdx.x;
    int C = (E + gridDim.x - 1) / gridDim.x;
    int lo = b * C, hi = lo + C; if (hi > E) hi = E;
    for (int k = threadIdx.x; k < K; k += 256)
        lbase[k] = bstart[k] + ghist[k * BINB + b];
    __syncthreads();
    for (int e = lo + threadIdx.x; e < hi; e += 256) {
        int d = dst[e];
        int k = d >> 10;
        int p = atomicAdd(&lbase[k], 1);
        staged[p] = (unsigned int)src[e] | ((unsigned int)(d & (NPB - 1)) << 17);
    }
}

__global__ __launch_bounds__(1024)
void build_kernel(const unsigned int* __restrict__ staged, const int* __restrict__ bstart,
                  int* __restrict__ offs, int* __restrict__ csr, int N) {
    __shared__ int cnt[1024];
    __shared__ int buf[1024];
    int k = blockIdx.x;
    int t = threadIdx.x;
    int e0 = bstart[k], e1 = bstart[k + 1];
    cnt[t] = 0;
    __syncthreads();
    for (int p = e0 + t; p < e1; p += 1024)
        atomicAdd(&cnt[staged[p] >> 17], 1);
    __syncthreads();
    int myc = cnt[t];
    int* a = cnt; int* bb = buf;
    for (int off = 1; off < 1024; off <<= 1) {
        int v = a[t];
        if (t >= off) v += a[t - off];
        bb[t] = v;
        __syncthreads();
        int* tmp = a; a = bb; bb = tmp;
    }
    int excl = a[t] - myc;
    int node = k * NPB + t;
    if (node < N) offs[node] = e0 + excl;
    bb[t] = excl;
    __syncthreads();
    for (int p = e0 + t; p < e1; p += 1024) {
        unsigned int v = staged[p];
        int n = v >> 17;
        int q = atomicAdd(&bb[n], 1);
        csr[e0 + q] = (int)(v & 0x1FFFFu);
    }
}

// ---------------- stem MFMA GEMM (f32 input, prepacked W image, 64 cols) ----------------

__global__ __launch_bounds__(256)
void gemm_mfma_stem(const float* __restrict__ feat, const float* __restrict__ pos,
                    const unsigned int* __restrict__ Wimg, const float* __restrict__ bi,
                    unsigned short* __restrict__ U, int N) {
    __shared__ __attribute__((aligned(16))) unsigned short As[64][104];
    __shared__ __attribute__((aligned(16))) unsigned short Bs[64][104];
    int row0 = blockIdx.x * 64;
    int tid  = threadIdx.x;

    for (int idx = tid; idx < 64 * 52; idx += 256) {
        int r = idx / 52, k2 = idx - r * 52;
        int grow = row0 + r;
        unsigned int pack = 0;
        if (grow < N && k2 <= 32) {
            float v0, v1;
            if (k2 < 32) {
                f2 v = *(const f2*)&feat[(size_t)grow * 64 + k2 * 2];
                v0 = v.x; v1 = v.y;
            } else {
                v0 = pos[(size_t)grow * 3 + 0];
                v1 = pos[(size_t)grow * 3 + 1];
            }
            pack = packbf(v0, v1);
        }
        *(unsigned int*)&As[r][k2 * 2] = pack;
    }
    // B: straight 16B copy of the prepacked image (64*52 u32 = 832 uint4)
    for (int idx = tid; idx < 832; idx += 256)
        ((u32x4*)&Bs[0][0])[idx] = ((const u32x4*)Wimg)[idx];
    __syncthreads();

    int lane = tid & 63;
    int wv   = tid >> 6;
    int l16  = lane & 15;
    int kg   = lane >> 4;
    int wr   = wv * 16;

    f4 acc[4];
#pragma unroll
    for (int t = 0; t < 4; ++t) acc[t] = (f4)(0.f);

#pragma unroll
    for (int s = 0; s < 3; ++s) {
        s8 a = *(const s8*)&As[wr + l16][s * 32 + kg * 8];
#pragma unroll
        for (int t = 0; t < 4; ++t) {
            s8 b = *(const s8*)&Bs[t * 16 + l16][s * 32 + kg * 8];
            acc[t] = __builtin_amdgcn_mfma_f32_16x16x32_bf16(a, b, acc[t], 0, 0, 0);
        }
    }

#pragma unroll
    for (int t = 0; t < 4; ++t) {
        int gc = t * 16 + l16;
        float bv = bi[gc];
#pragma unroll
        for (int r = 0; r < 4; ++r) {
            int grow = row0 + wr + kg * 4 + r;
            if (grow < N)
                U[(size_t)grow * 64 + gc] = f2bf(acc[t][r] + bv);
        }
    }
}

// ---------------- dual MFMA GEMM: one A-stage, 128 output cols, prepacked W image ----------------

__global__ __launch_bounds__(256)
void gemm_mfma_dual(const unsigned int* __restrict__ sb, const float* __restrict__ pos,
                    const unsigned int* __restrict__ Wimg,
                    const float* __restrict__ ba, const float* __restrict__ bb,
                    int wbaseB, int WROWSB, const float* __restrict__ ab,
                    unsigned short* __restrict__ U, int N, int ldU) {
    __shared__ __attribute__((aligned(16))) unsigned short As[64][104];
    __shared__ __attribute__((aligned(16))) unsigned short Bs[128][104];
    int row0 = blockIdx.x * 64;
    int tid  = threadIdx.x;

    for (int idx = tid; idx < 64 * 52; idx += 256) {
        int r = idx / 52, k2 = idx - r * 52;
        int grow = row0 + r;
        unsigned int pack = 0;
        if (grow < N && k2 <= 32) {
            float v0, v1;
            if (k2 < 32) {
                f2 v = bf2(sb[(size_t)grow * 32 + k2]);
                int k = k2 * 2;
                v0 = fmaxf(0.f, v.x * ab[k] + ab[64 + k]);
                v1 = fmaxf(0.f, v.y * ab[k + 1] + ab[64 + k + 1]);
            } else {
                v0 = pos[(size_t)grow * 3 + 0];
                v1 = pos[(size_t)grow * 3 + 1];
            }
            pack = packbf(v0, v1);
        }
        *(unsigned int*)&As[r][k2 * 2] = pack;
    }
    // B: straight 16B copy of the prepacked image (128*52 u32 = 1664 uint4)
    for (int idx = tid; idx < 1664; idx += 256)
        ((u32x4*)&Bs[0][0])[idx] = ((const u32x4*)Wimg)[idx];
    __syncthreads();

    int lane = tid & 63;
    int wv   = tid >> 6;
    int l16  = lane & 15;
    int kg   = lane >> 4;
    int wr   = wv * 16;

    f4 acc[8];
#pragma unroll
    for (int t = 0; t < 8; ++t) acc[t] = (f4)(0.f);

#pragma unroll
    for (int s = 0; s < 3; ++s) {
        s8 a = *(const s8*)&As[wr + l16][s * 32 + kg * 8];
#pragma unroll
        for (int t = 0; t < 8; ++t) {
            s8 b = *(const s8*)&Bs[t * 16 + l16][s * 32 + kg * 8];
            acc[t] = __builtin_amdgcn_mfma_f32_16x16x32_bf16(a, b, acc[t], 0, 0, 0);
        }
    }

#pragma unroll
    for (int t = 0; t < 8; ++t) {
        int cl = t * 16 + l16;
        float bv;
        bool valid;
        if (cl < 64) { bv = ba[cl]; valid = true; }
        else {
            int wrow = wbaseB + (cl - 64);
            valid = wrow < WROWSB;
            bv = valid ? bb[wrow] : 0.f;
        }
        if (!valid) continue;
#pragma unroll
        for (int r = 0; r < 4; ++r) {
            int grow = row0 + wr + kg * 4 + r;
            if (grow < N)
                U[(size_t)grow * ldU + cl] = f2bf(acc[t][r] + bv);
        }
    }
}

// ---------------- reg(4)+obj(1) heads (bf16 in, bf16 out -> uAll cols 102..106) ----------------

__global__ __launch_bounds__(256)
void gemm_regobj(const unsigned int* __restrict__ sb, const float* __restrict__ pos,
                 const float* __restrict__ Wr, const float* __restrict__ br,
                 const float* __restrict__ Wo, const float* __restrict__ bo,
                 const float* __restrict__ ab, unsigned short* __restrict__ uAll, int N) {
    __shared__ __attribute__((aligned(16))) float As[64][68];
    __shared__ float Wt[66][5];
    int row0 = blockIdx.x * 64;
    int tid  = threadIdx.x;
    for (int idx = tid; idx < 64 * 33; idx += 256) {
        int r = idx / 33, k2 = idx - r * 33;
        int grow = row0 + r;
        float v0 = 0.f, v1 = 0.f;
        if (grow < N) {
            if (k2 < 32) {
                f2 v = bf2(sb[(size_t)grow * 32 + k2]);
                int k = k2 * 2;
                v0 = fmaxf(0.f, v.x * ab[k] + ab[64 + k]);
                v1 = fmaxf(0.f, v.y * ab[k + 1] + ab[64 + k + 1]);
            } else {
                v0 = pos[(size_t)grow * 3 + 0];
                v1 = pos[(size_t)grow * 3 + 1];
            }
        }
        As[r][k2 * 2]     = v0;
        As[r][k2 * 2 + 1] = v1;
    }
    for (int idx = tid; idx < 66 * 5; idx += 256) {
        int c = idx / 66, k = idx - c * 66;
        Wt[k][c] = (c < 4) ? Wr[(size_t)c * 66 + k] : Wo[k];
    }
    __syncthreads();
    int r  = tid & 63;
    int cs = tid >> 6;     // 0..3
    int grow = row0 + r;
    if (grow >= N) return;
    float acc = 0.f, acco = 0.f;
    for (int k = 0; k < 66; ++k) {
        float a = As[r][k];
        acc += a * Wt[k][cs];
        if (cs == 0) acco += a * Wt[k][4];
    }
    uAll[(size_t)grow * LDALL + 102 + cs] = f2bf(acc + br[cs]);
    if (cs == 0) uAll[(size_t)grow * LDALL + 106] = f2bf(acco + bo[0]);
}

// ---------------- segment max, 64ch bf16 (stem): 1 node/wave, clamped 8-edge blocks ----------------

__global__ __launch_bounds__(256)
void segmax64b(const unsigned short* __restrict__ U, const float* __restrict__ pos,
               const float* __restrict__ W, const int* __restrict__ offs,
               const int* __restrict__ csr, unsigned int* __restrict__ outb,
               float* __restrict__ partials, int N) {
    int t    = threadIdx.x;
    int lane = t & 63;
    int h    = lane >> 5;       // edge parity handled by this half-wave
    int cl   = lane & 31;
    int c0   = cl * 2;
    int wv   = t >> 6;
    int gw   = blockIdx.x * 4 + wv;
    int nw   = gridDim.x * 4;
    float wa0 = W[c0 * 66 + 64],       wa1 = W[c0 * 66 + 65];
    float wb0 = W[(c0 + 1) * 66 + 64], wb1 = W[(c0 + 1) * 66 + 65];
    f2 sum = {0.f, 0.f}, sq = {0.f, 0.f};
    for (int i = gw; i < N; i += nw) {
        int s0 = offs[i], s1 = offs[i + 1];
        f2 m = { -INFINITY, -INFINITY };
        for (int e = s0; e < s1; e += 8) {
            unsigned int v[4];
#pragma unroll
            for (int u = 0; u < 4; ++u) {
                int ee = e + 2 * u + h;
                if (ee > s1 - 1) ee = s1 - 1;
                v[u] = *(const unsigned int*)&U[(size_t)csr[ee] * 64 + c0];
            }
#pragma unroll
            for (int u = 0; u < 4; ++u) {
                f2 f = bf2(v[u]);
                m.x = fmaxf(m.x, f.x);
                m.y = fmaxf(m.y, f.y);
            }
        }
        m.x = fmaxf(m.x, __shfl_xor(m.x, 32));
        m.y = fmaxf(m.y, __shfl_xor(m.y, 32));
        if (h == 0) {
            float p0 = pos[i * 3], p1 = pos[i * 3 + 1];
            f2 val = {0.f, 0.f};
            if (s1 > s0) {
                val.x = m.x - (p0 * wa0 + p1 * wa1);
                val.y = m.y - (p0 * wb0 + p1 * wb1);
            }
            outb[(size_t)i * 32 + cl] = packbf(val.x, val.y);
            sum.x += val.x; sum.y += val.y;
            sq.x  += val.x * val.x; sq.y += val.y * val.y;
        }
    }
    __shared__ f2 ls[4][32];
    __shared__ f2 lq[4][32];
    if (h == 0) { ls[wv][cl] = sum; lq[wv][cl] = sq; }
    __syncthreads();
    if (t < 32) {
        f2 S = {0.f, 0.f}, Q = {0.f, 0.f};
#pragma unroll
        for (int w = 0; w < 4; ++w) {
            f2 a = ls[w][t]; S.x += a.x; S.y += a.y;
            f2 c = lq[w][t]; Q.x += c.x; Q.y += c.y;
        }
        partials[blockIdx.x * 128 + 2 * t]       = S.x;
        partials[blockIdx.x * 128 + 2 * t + 1]   = S.y;
        partials[blockIdx.x * 128 + 64 + 2 * t]  = Q.x;
        partials[blockIdx.x * 128 + 65 + 2 * t]  = Q.y;
    }
}

// ---------------- fused dual segment max: 1 node/wave, clamped 8-edge blocks ----------------

__global__ __launch_bounds__(256)
void segmax_dual(const unsigned short* __restrict__ TD, const float* __restrict__ pos,
                 const float* __restrict__ W1, const float* __restrict__ W2,
                 const int* __restrict__ offs, const int* __restrict__ csr,
                 unsigned int* __restrict__ S1o, unsigned int* __restrict__ S2o,
                 float* __restrict__ partials, int N) {
    int t    = threadIdx.x;
    int lane = t & 63;
    int cl   = lane & 31;
    int c0   = cl * 2;
    int wv   = t >> 6;
    int gw   = blockIdx.x * 4 + wv;
    int nw   = gridDim.x * 4;
    const float* Ws = (lane >= 32) ? W2 : W1;
    float wa0 = Ws[c0 * 66 + 64],       wa1 = Ws[c0 * 66 + 65];
    float wb0 = Ws[(c0 + 1) * 66 + 64], wb1 = Ws[(c0 + 1) * 66 + 65];
    f2 sum = {0.f, 0.f}, sq = {0.f, 0.f};
    for (int i = gw; i < N; i += nw) {
        int s0 = offs[i], s1 = offs[i + 1];
        f2 m = { -INFINITY, -INFINITY };
        for (int e = s0; e < s1; e += 8) {
            unsigned int v[8];
#pragma unroll
            for (int u = 0; u < 8; ++u) {
                int ee = e + u;
                if (ee > s1 - 1) ee = s1 - 1;
                v[u] = *(const unsigned int*)&TD[(size_t)csr[ee] * 128 + lane * 2];
            }
#pragma unroll
            for (int u = 0; u < 8; ++u) {
                f2 f = bf2(v[u]);
                m.x = fmaxf(m.x, f.x);
                m.y = fmaxf(m.y, f.y);
            }
        }
        float p0 = pos[i * 3], p1 = pos[i * 3 + 1];
        f2 val = {0.f, 0.f};
        if (s1 > s0) {
            val.x = m.x - (p0 * wa0 + p1 * wa1);
            val.y = m.y - (p0 * wb0 + p1 * wb1);
        }
        if (lane < 32) S1o[(size_t)i * 32 + cl] = packbf(val.x, val.y);
        else           S2o[(size_t)i * 32 + cl] = packbf(val.x, val.y);
        sum.x += val.x; sum.y += val.y;
        sq.x  += val.x * val.x; sq.y += val.y * val.y;
    }
    __shared__ f2 ls[4][64];
    __shared__ f2 lq[4][64];
    ls[wv][lane] = sum; lq[wv][lane] = sq;
    __syncthreads();
    if (t < 64) {
        f2 S = {0.f, 0.f}, Q = {0.f, 0.f};
#pragma unroll
        for (int w = 0; w < 4; ++w) {
            f2 a = ls[w][t]; S.x += a.x; S.y += a.y;
            f2 c = lq[w][t]; Q.x += c.x; Q.y += c.y;
        }
        float* P = &partials[blockIdx.x * 256];
        if (t < 32) {
            P[2 * t] = S.x;        P[2 * t + 1] = S.y;
            P[64 + 2 * t] = Q.x;   P[65 + 2 * t] = Q.y;
        } else {
            int u = t - 32;
            P[128 + 2 * u] = S.x;  P[129 + 2 * u] = S.y;
            P[192 + 2 * u] = Q.x;  P[193 + 2 * u] = Q.y;
        }
    }
}

// ---------------- unified heads segment max: cls(0..100) + reg(102..105) + obj(106) ----------------

__global__ __launch_bounds__(256)
void segmax_all(const unsigned short* __restrict__ U, const float* __restrict__ pos,
                const float* __restrict__ Wc, const float* __restrict__ Wr,
                const float* __restrict__ Wo, const int* __restrict__ offs,
                const int* __restrict__ csr, float* __restrict__ out_cls,
                float* __restrict__ out_reg, float* __restrict__ out_obj, int N) {
    int lane = threadIdx.x & 63;
    if (lane >= 54) return;               // no barriers below: safe
    int c0 = lane * 2;
    int wv = threadIdx.x >> 6;
    int gg = blockIdx.x * 4 + wv;
    int ng = gridDim.x * 4;
    float w0x, w0y, w1x, w1y;
    if (lane < 51) {
        w0x = Wc[c0 * 66 + 64]; w0y = Wc[c0 * 66 + 65];
        int c1 = c0 + 1;
        w1x = (c1 < NCLS) ? Wc[c1 * 66 + 64] : 0.f;
        w1y = (c1 < NCLS) ? Wc[c1 * 66 + 65] : 0.f;
    } else if (lane < 53) {
        int rc = (lane - 51) * 2;
        w0x = Wr[rc * 66 + 64];       w0y = Wr[rc * 66 + 65];
        w1x = Wr[(rc + 1) * 66 + 64]; w1y = Wr[(rc + 1) * 66 + 65];
    } else {
        w0x = Wo[64]; w0y = Wo[65]; w1x = 0.f; w1y = 0.f;
    }
    for (int i = gg; i < N; i += ng) {
        int s0 = offs[i], s1 = offs[i + 1];
        f2 m = { -INFINITY, -INFINITY };
        for (int e = s0; e < s1; e += 8) {
            unsigned int v[8];
#pragma unroll
            for (int u = 0; u < 8; ++u) {
                int ee = e + u;
                if (ee > s1 - 1) ee = s1 - 1;
                v[u] = *(const unsigned int*)&U[(size_t)csr[ee] * LDALL + c0];
            }
#pragma unroll
            for (int u = 0; u < 8; ++u) {
                f2 f = bf2(v[u]);
                m.x = fmaxf(m.x, f.x);
                m.y = fmaxf(m.y, f.y);
            }
        }
        float p0 = pos[i * 3], p1 = pos[i * 3 + 1];
        float va = 0.f, vb = 0.f;
        if (s1 > s0) {
            va = m.x - (p0 * w0x + p1 * w0y);
            vb = m.y - (p0 * w1x + p1 * w1y);
        }
        if (lane < 50) {
            out_cls[(size_t)i * NCLS + c0]     = va;
            out_cls[(size_t)i * NCLS + c0 + 1] = vb;
        } else if (lane == 50) {
            out_cls[(size_t)i * NCLS + 100] = va;
        } else if (lane == 51) {
            out_reg[(size_t)i * 4 + 0] = va;
            out_reg[(size_t)i * 4 + 1] = vb;
        } else if (lane == 52) {
            out_reg[(size_t)i * 4 + 2] = va;
            out_reg[(size_t)i * 4 + 3] = vb;
        } else {
            out_obj[i] = va;
        }
    }
}

// ---------------- BN finalize: single (stem) and dual (conv1+conv2) ----------------

__global__ __launch_bounds__(1024)
void bn_finalize(const float* __restrict__ partials, int N,
                 const float* __restrict__ g, const float* __restrict__ be,
                 float* __restrict__ ab) {
    __shared__ double ls[16][64];
    __shared__ double lq[16][64];
    int t = threadIdx.x;
    int c  = t & 63;
    int gr = t >> 6;
    double s = 0.0, q = 0.0;
#pragma unroll 8
    for (int b = 0; b < SEG_BLOCKS / 16; ++b) {
        int blk = gr * (SEG_BLOCKS / 16) + b;
        s += (double)partials[blk * 128 + c];
        q += (double)partials[blk * 128 + 64 + c];
    }
    ls[gr][c] = s; lq[gr][c] = q;
    __syncthreads();
    if (gr == 0) {
        double ss = 0.0, qq = 0.0;
#pragma unroll
        for (int i = 0; i < 16; ++i) { ss += ls[i][c]; qq += lq[i][c]; }
        double invN = 1.0 / (double)N;
        float m = (float)(ss * invN);
        float v = (float)(qq * invN) - m * m;
        float a = g[c] * rsqrtf(v + 1e-5f);
        ab[c]      = a;
        ab[64 + c] = be[c] - m * a;
    }
}

__global__ __launch_bounds__(1024)
void bn_finalize2(const float* __restrict__ partials, int N,
                  const float* __restrict__ g1, const float* __restrict__ be1,
                  const float* __restrict__ g2, const float* __restrict__ be2,
                  float* __restrict__ ab1, float* __restrict__ ab2) {
    __shared__ double L[4][16][64];
    int t = threadIdx.x;
    int c  = t & 63;
    int gr = t >> 6;
    double s1 = 0.0, q1 = 0.0, s2 = 0.0, q2 = 0.0;
#pragma unroll 8
    for (int b = 0; b < SEG_BLOCKS / 16; ++b) {
        const float* P = &partials[(size_t)(gr * (SEG_BLOCKS / 16) + b) * 256];
        s1 += (double)P[c];        q1 += (double)P[64 + c];
        s2 += (double)P[128 + c];  q2 += (double)P[192 + c];
    }
    L[0][gr][c] = s1; L[1][gr][c] = q1; L[2][gr][c] = s2; L[3][gr][c] = q2;
    __syncthreads();
    if (gr == 0) {
        double S1 = 0, Q1 = 0, S2 = 0, Q2 = 0;
#pragma unroll
        for (int i = 0; i < 16; ++i) {
            S1 += L[0][i][c]; Q1 += L[1][i][c];
            S2 += L[2][i][c]; Q2 += L[3][i][c];
        }
        double invN = 1.0 / (double)N;
        float m1 = (float)(S1 * invN);
        float v1 = (float)(Q1 * invN) - m1 * m1;
        float a1 = g1[c] * rsqrtf(v1 + 1e-5f);
        ab1[c]      = a1;
        ab1[64 + c] = be1[c] - m1 * a1;
        float m2 = (float)(S2 * invN);
        float v2 = (float)(Q2 * invN) - m2 * m2;
        float a2 = g2[c] * rsqrtf(v2 + 1e-5f);
        ab2[c]      = a2;
        ab2[64 + c] = be2[c] - m2 * a2;
    }
}

// ---------------- launch ----------------

extern "C" void kernel_launch(void* const* d_in, const int* in_sizes, int n_in,
                              void* d_out, int out_size, void* d_ws, size_t ws_size,
                              hipStream_t stream) {
    const float* x       = (const float*)d_in[0];
    const float* pos     = (const float*)d_in[1];
    const int*   ei      = (const int*)d_in[2];
    const float* W_stem  = (const float*)d_in[3];
    const float* b_stem  = (const float*)d_in[4];
    const float* W_conv1 = (const float*)d_in[5];
    const float* b_conv1 = (const float*)d_in[6];
    const float* W_conv2 = (const float*)d_in[7];
    const float* b_conv2 = (const float*)d_in[8];
    const float* W_regr  = (const float*)d_in[9];
    const float* b_regr  = (const float*)d_in[10];
    const float* W_cls   = (const float*)d_in[11];
    const float* b_cls   = (const float*)d_in[12];
    const float* W_obj   = (const float*)d_in[13];
    const float* b_obj   = (const float*)d_in[14];
    const float* g_stem  = (const float*)d_in[15];
    const float* be_stem = (const float*)d_in[16];
    const float* g_conv1 = (const float*)d_in[17];
    const float* be_conv1= (const float*)d_in[18];
    const float* g_conv2 = (const float*)d_in[19];
    const float* be_conv2= (const float*)d_in[20];

    const int N = in_sizes[0] / 64;
    const int E = in_sizes[2] / 2;
    const int* src = ei;
    const int* dst = ei + E;
    const int K = (N + NPB - 1) / NPB;

    // ---- workspace layout (256B-aligned regions) ----
    char* ws = (char*)d_ws;
    size_t off = 0;
    auto carve = [&](size_t bytes) -> char* {
        char* p = ws + off;
        off += (bytes + 255) & ~(size_t)255;
        return p;
    };
    int*   offs     = (int*)carve((size_t)(N + 1) * 4);
    int*   csr      = (int*)carve((size_t)E * 4);
    unsigned int* staged = (unsigned int*)carve((size_t)E * 4);
    int*   ghist    = (int*)carve((size_t)KMAX * BINB * 4);
    int*   tot      = (int*)carve((size_t)KMAX * 4);
    int*   bstart   = (int*)carve((size_t)(KMAX + 1) * 4);
    unsigned int* wimg = (unsigned int*)carve((size_t)320 * 52 * 4);  // prepacked W images
    unsigned int* S1b = (unsigned int*)carve((size_t)N * 32 * 4);   // bf16 [N][64] as u32[N][32]
    unsigned int* S2b = (unsigned int*)carve((size_t)N * 32 * 4);
    unsigned short* T1 = (unsigned short*)carve((size_t)N * 64 * 2);   // U_stem ; (T1+TD) reused as uAll
    unsigned short* TD = (unsigned short*)carve((size_t)N * 128 * 2);  // U1|U2 interleaved
    float* partials = (float*)carve((size_t)SEG_BLOCKS * 256 * 4);
    float* abS      = (float*)carve(128 * 4);
    float* ab1      = (float*)carve(128 * 4);
    float* ab2      = (float*)carve(128 * 4);
    unsigned short* uAll = T1;   // N*128 bf16 = 25.6MB <= T1+TD (38.4MB, contiguous)

    const unsigned int* wimg_stem = wimg;                 // 64 rows
    const unsigned int* wimg_conv = wimg + 64 * 52;       // 128 rows (W1|W2)
    const unsigned int* wimg_cls  = wimg + 192 * 52;      // 128 rows (Wc, valid<101)

    float* out_cls = (float*)d_out;                       // N x 101
    float* out_reg = out_cls + (size_t)N * NCLS;          // N x 4
    float* out_obj = out_reg + (size_t)N * 4;             // N x 1

    const dim3 blk(256);

    // ---- weight image prep (independent of everything else) ----
    wprep_kernel<<<(320 * 52 + 255) / 256, blk, 0, stream>>>(W_stem, W_conv1, W_conv2, W_cls, wimg);

    // ---- CSR build ----
    hist_kernel<<<BINB, blk, 0, stream>>>(dst, ghist, E, K);
    scan_hist_kernel<<<K, BINB, 0, stream>>>(ghist, tot, K);
    scan_tot_kernel<<<1, KMAX, 0, stream>>>(tot, bstart, offs, K, N, E);
    scatter_kernel<<<BINB, blk, 0, stream>>>(src, dst, ghist, bstart, staged, E, K);
    build_kernel<<<K, 1024, 0, stream>>>(staged, bstart, offs, csr, N);

    const int ng64 = (N + 63) / 64;

    // ---- stem: f32 x -> T1 (bf16) ----
    gemm_mfma_stem<<<ng64, blk, 0, stream>>>(x, pos, wimg_stem, b_stem, T1, N);
    segmax64b<<<SEG_BLOCKS, blk, 0, stream>>>(T1, pos, W_stem, offs, csr, S1b, partials, N);
    bn_finalize<<<1, 1024, 0, stream>>>(partials, N, g_stem, be_stem, abS);

    // ---- conv1 + conv2: ONE launch, A staged once -> interleaved TD ----
    gemm_mfma_dual<<<ng64, blk, 0, stream>>>(S1b, pos, wimg_conv, b_conv1, b_conv2,
                                             0, 64, abS, TD, N, 128);
    segmax_dual<<<SEG_BLOCKS, blk, 0, stream>>>(TD, pos, W_conv1, W_conv2, offs, csr,
                                                S1b, S2b, partials, N);
    bn_finalize2<<<1, 1024, 0, stream>>>(partials, N, g_conv1, be_conv1,
                                         g_conv2, be_conv2, ab1, ab2);

    // ---- heads: reg/obj -> uAll cols 102.. ; cls (both column halves, one launch) ----
    gemm_regobj<<<ng64, blk, 0, stream>>>(S1b, pos, W_regr, b_regr,
                                          W_obj, b_obj, ab1, uAll, N);
    gemm_mfma_dual<<<ng64, blk, 0, stream>>>(S2b, pos, wimg_cls, b_cls, b_cls,
                                             64, NCLS, ab2, uAll, N, LDALL);

    // ---- unified gather for all three outputs ----
    segmax_all<<<SEG_BLOCKS, blk, 0, stream>>>(uAll, pos, W_cls, W_regr, W_obj,
                                               offs, csr, out_cls, out_reg, out_obj, N);
}